// Round 2
// baseline (4948.529 us; speedup 1.0000x reference)
//
#include <hip/hip_runtime.h>

#define HH 128
#define EAA 16
#define NNODES 100000
#define NEDGES 500000

typedef unsigned int u32;
typedef unsigned short u16;

__device__ __forceinline__ float bf_lo(u32 v){ return __builtin_bit_cast(float, (u32)(v << 16)); }
__device__ __forceinline__ float bf_hi(u32 v){ return __builtin_bit_cast(float, (u32)(v & 0xffff0000u)); }
__device__ __forceinline__ float bf1(u16 v){ return __builtin_bit_cast(float, (u32)(((u32)v) << 16)); }
__device__ __forceinline__ u16 f2bf(float f){
  u32 x = __builtin_bit_cast(u32, f);
  return (u16)((x + 0x7fffu + ((x >> 16) & 1u)) >> 16);
}
__device__ __forceinline__ float rdlane(float v, int l){
  return __builtin_bit_cast(float, __builtin_amdgcn_readlane(__builtin_bit_cast(int, v), l));
}
__device__ __forceinline__ float sigm(float x){ return 1.0f / (1.0f + __expf(-x)); }

// ---- dtype-generic helpers. DT==0: float32 tensors. DT==1: bf16 tensors. ----
template<int DT> __device__ __forceinline__ float ldf(const void* p, size_t i){
  return (DT == 0) ? ((const float*)p)[i] : bf1(((const u16*)p)[i]);
}
// stage n elements of a weight matrix into LDS as packed bf16
template<int DT> __device__ __forceinline__ void stage_w(u16* dst, const void* src, int n, int tid, int nthr){
  if (DT == 0){
    const float2* s = (const float2*)src;
    u32* d = (u32*)dst;
    for (int i = tid; i < n/2; i += nthr){
      float2 v = s[i];
      d[i] = ((u32)f2bf(v.y) << 16) | (u32)f2bf(v.x);
    }
  } else {
    for (int i = tid; i < n/8; i += nthr)
      ((uint4*)dst)[i] = ((const uint4*)src)[i];
  }
}

// dtype probe: h_ln_g is all ones. f32 word0 = 0x3F800000, bf16 pair = 0x3F803F80.
__global__ void dtype_probe(const u32* __restrict__ lng, int* __restrict__ flag){
  *flag = (lng[0] == 0x3F800000u) ? 0 : 1;
}

// ---------------------------------------------------------------------------
// Edge messages: per edge e:
//   src = srcN[edges[2e+srcCol]]; cat=[src, eattr[e]]
//   y = silu(cat@w1+b1); g = sigmoid(y@w2+b2); msg = (src@mw+mb)*g
//   atomicAdd agg[edges[2e+(1-srcCol)]] += msg
// One wave per edge; lane owns output cols 2l, 2l+1; cat broadcast via readlane.
// ---------------------------------------------------------------------------
template<int DT>
__global__ __launch_bounds__(1024) void edge_msgs(
    const int* __restrict__ flag,
    const void* __restrict__ srcN, const int* __restrict__ edges,
    const void* __restrict__ eattr,
    const void* __restrict__ w1, const void* __restrict__ b1,
    const void* __restrict__ w2, const void* __restrict__ b2,
    const void* __restrict__ mw, const void* __restrict__ mb,
    float* __restrict__ agg, int srcCol)
{
  if (*flag != DT) return;

  __shared__ alignas(16) u16 w1s[(HH + EAA) * HH];
  __shared__ alignas(16) u16 w2s[HH * HH];
  __shared__ alignas(16) u16 mws[HH * HH];
  __shared__ float b1s[HH], b2s[HH], mbs[HH];

  const int tid = threadIdx.x;
  stage_w<DT>(w1s, w1, (HH + EAA) * HH, tid, 1024);
  stage_w<DT>(w2s, w2, HH * HH, tid, 1024);
  stage_w<DT>(mws, mw, HH * HH, tid, 1024);
  if (tid < HH) { b1s[tid] = ldf<DT>(b1, tid); b2s[tid] = ldf<DT>(b2, tid); mbs[tid] = ldf<DT>(mb, tid); }
  __syncthreads();

  const int lane = tid & 63;
  const int wid  = tid >> 6;
  const int gw   = blockIdx.x * 16 + wid;
  const int nw   = gridDim.x * 16;
  const int dstCol = 1 - srcCol;

  for (int e = gw; e < NEDGES; e += nw) {
    const int s = edges[2 * e + srcCol];
    const int d = edges[2 * e + dstCol];
    const size_t sb = (size_t)s * HH;
    float c0 = ldf<DT>(srcN, sb + lane);
    float c1 = ldf<DT>(srcN, sb + lane + 64);
    float c2 = (lane < EAA) ? ldf<DT>(eattr, (size_t)e * EAA + lane) : 0.0f;

    // y = silu(cat @ w1 + b1)
    float a0 = b1s[2 * lane], a1 = b1s[2 * lane + 1];
#pragma unroll 8
    for (int k = 0; k < 64; k++) {
      float ck = rdlane(c0, k);
      u32 wv = *(const u32*)(w1s + k * HH + 2 * lane);
      a0 = fmaf(ck, bf_lo(wv), a0); a1 = fmaf(ck, bf_hi(wv), a1);
    }
#pragma unroll 8
    for (int k = 0; k < 64; k++) {
      float ck = rdlane(c1, k);
      u32 wv = *(const u32*)(w1s + (k + 64) * HH + 2 * lane);
      a0 = fmaf(ck, bf_lo(wv), a0); a1 = fmaf(ck, bf_hi(wv), a1);
    }
#pragma unroll 8
    for (int k = 0; k < EAA; k++) {
      float ck = rdlane(c2, k);
      u32 wv = *(const u32*)(w1s + (k + 128) * HH + 2 * lane);
      a0 = fmaf(ck, bf_lo(wv), a0); a1 = fmaf(ck, bf_hi(wv), a1);
    }
    float y0 = a0 * sigm(a0);
    float y1 = a1 * sigm(a1);

    // g = y @ w2 + b2 ; m = src @ mw + mb
    float g0 = b2s[2 * lane], g1 = b2s[2 * lane + 1];
    float m0 = mbs[2 * lane], m1 = mbs[2 * lane + 1];
#pragma unroll 4
    for (int k = 0; k < 64; k++) {
      float ye = rdlane(y0, k);
      float yo = rdlane(y1, k);
      u32 w2a = *(const u32*)(w2s + (2 * k) * HH + 2 * lane);
      u32 w2b = *(const u32*)(w2s + (2 * k + 1) * HH + 2 * lane);
      g0 = fmaf(ye, bf_lo(w2a), g0); g1 = fmaf(ye, bf_hi(w2a), g1);
      g0 = fmaf(yo, bf_lo(w2b), g0); g1 = fmaf(yo, bf_hi(w2b), g1);
      float se = rdlane(c0, k);
      float so = rdlane(c1, k);
      u32 mwa = *(const u32*)(mws + k * HH + 2 * lane);
      u32 mwb = *(const u32*)(mws + (k + 64) * HH + 2 * lane);
      m0 = fmaf(se, bf_lo(mwa), m0); m1 = fmaf(se, bf_hi(mwa), m1);
      m0 = fmaf(so, bf_lo(mwb), m0); m1 = fmaf(so, bf_hi(mwb), m1);
    }
    float v0 = m0 * sigm(g0);
    float v1 = m1 * sigm(g1);

    float* ap = agg + (size_t)d * HH + 2 * lane;
    atomicAdd(ap, v0);
    atomicAdd(ap + 1, v1);
  }
}

// ---------------------------------------------------------------------------
// Node update: x = hin + relu([hin, agg] @ w1 + b1) @ w2 + b2 ; out = LN(x)
// ---------------------------------------------------------------------------
template<int DT>
__global__ __launch_bounds__(1024) void node_upd(
    const int* __restrict__ flag,
    const void* __restrict__ hin, const float* __restrict__ agg,
    const void* __restrict__ w1, const void* __restrict__ b1,
    const void* __restrict__ w2, const void* __restrict__ b2,
    const void* __restrict__ lng, const void* __restrict__ lnb,
    void* __restrict__ out)
{
  if (*flag != DT) return;

  __shared__ alignas(16) u16 w1s[2 * HH * HH];
  __shared__ alignas(16) u16 w2s[HH * HH];
  __shared__ float b1s[HH], b2s[HH], gs[HH], bs[HH];

  const int tid = threadIdx.x;
  stage_w<DT>(w1s, w1, 2 * HH * HH, tid, 1024);
  stage_w<DT>(w2s, w2, HH * HH, tid, 1024);
  if (tid < HH) { b1s[tid] = ldf<DT>(b1, tid); b2s[tid] = ldf<DT>(b2, tid);
                  gs[tid] = ldf<DT>(lng, tid); bs[tid] = ldf<DT>(lnb, tid); }
  __syncthreads();

  const int lane = tid & 63;
  const int wid  = tid >> 6;
  const int gw   = blockIdx.x * 16 + wid;
  const int nw   = gridDim.x * 16;

  for (int n = gw; n < NNODES; n += nw) {
    const size_t hb = (size_t)n * HH;
    const float* ap = agg + hb;
    float c0 = ldf<DT>(hin, hb + lane);
    float c1 = ldf<DT>(hin, hb + lane + 64);
    float c2 = ap[lane];
    float c3 = ap[lane + 64];

    float a0 = b1s[2 * lane], a1 = b1s[2 * lane + 1];
#pragma unroll 8
    for (int k = 0; k < 64; k++) {
      float ck = rdlane(c0, k);
      u32 wv = *(const u32*)(w1s + k * HH + 2 * lane);
      a0 = fmaf(ck, bf_lo(wv), a0); a1 = fmaf(ck, bf_hi(wv), a1);
    }
#pragma unroll 8
    for (int k = 0; k < 64; k++) {
      float ck = rdlane(c1, k);
      u32 wv = *(const u32*)(w1s + (k + 64) * HH + 2 * lane);
      a0 = fmaf(ck, bf_lo(wv), a0); a1 = fmaf(ck, bf_hi(wv), a1);
    }
#pragma unroll 8
    for (int k = 0; k < 64; k++) {
      float ck = rdlane(c2, k);
      u32 wv = *(const u32*)(w1s + (k + 128) * HH + 2 * lane);
      a0 = fmaf(ck, bf_lo(wv), a0); a1 = fmaf(ck, bf_hi(wv), a1);
    }
#pragma unroll 8
    for (int k = 0; k < 64; k++) {
      float ck = rdlane(c3, k);
      u32 wv = *(const u32*)(w1s + (k + 192) * HH + 2 * lane);
      a0 = fmaf(ck, bf_lo(wv), a0); a1 = fmaf(ck, bf_hi(wv), a1);
    }
    float y0 = fmaxf(a0, 0.0f);
    float y1 = fmaxf(a1, 0.0f);

    float u0 = b2s[2 * lane], u1 = b2s[2 * lane + 1];
#pragma unroll 8
    for (int k = 0; k < 64; k++) {
      float ye = rdlane(y0, k);
      float yo = rdlane(y1, k);
      u32 w2a = *(const u32*)(w2s + (2 * k) * HH + 2 * lane);
      u32 w2b = *(const u32*)(w2s + (2 * k + 1) * HH + 2 * lane);
      u0 = fmaf(ye, bf_lo(w2a), u0); u1 = fmaf(ye, bf_hi(w2a), u1);
      u0 = fmaf(yo, bf_lo(w2b), u0); u1 = fmaf(yo, bf_hi(w2b), u1);
    }

    // residual
    float h0, h1;
    if (DT == 0) {
      float2 hv = *(const float2*)((const float*)hin + hb + 2 * lane);
      h0 = hv.x; h1 = hv.y;
    } else {
      u32 hv = *(const u32*)((const u16*)hin + hb + 2 * lane);
      h0 = bf_lo(hv); h1 = bf_hi(hv);
    }
    float x0 = h0 + u0;
    float x1 = h1 + u1;

    // layernorm over 128
    float sum = x0 + x1;
#pragma unroll
    for (int off = 32; off >= 1; off >>= 1) sum += __shfl_xor(sum, off, 64);
    float mu = sum * (1.0f / 128.0f);
    float dx0 = x0 - mu, dx1 = x1 - mu;
    float vs = dx0 * dx0 + dx1 * dx1;
#pragma unroll
    for (int off = 32; off >= 1; off >>= 1) vs += __shfl_xor(vs, off, 64);
    float inv = rsqrtf(vs * (1.0f / 128.0f) + 1e-5f);
    float o0 = dx0 * inv * gs[2 * lane]     + bs[2 * lane];
    float o1 = dx1 * inv * gs[2 * lane + 1] + bs[2 * lane + 1];

    if (DT == 0) {
      float2 ov; ov.x = o0; ov.y = o1;
      *(float2*)((float*)out + hb + 2 * lane) = ov;
    } else {
      u32 pk = ((u32)f2bf(o1) << 16) | (u32)f2bf(o0);
      *(u32*)((u16*)out + hb + 2 * lane) = pk;
    }
  }
}

extern "C" void kernel_launch(void* const* d_in, const int* in_sizes, int n_in,
                              void* d_out, int out_size, void* d_ws, size_t ws_size,
                              hipStream_t stream) {
  const void* h_hidden = d_in[0];
  const void* h_clue   = d_in[1];
  const int*  edges    = (const int*)d_in[2];
  const void* eattr    = d_in[3];
  const void* c2h_g_w1 = d_in[4];  const void* c2h_g_b1 = d_in[5];
  const void* c2h_g_w2 = d_in[6];  const void* c2h_g_b2 = d_in[7];
  const void* c2h_m_w  = d_in[8];  const void* c2h_m_b  = d_in[9];
  const void* h_u_w1   = d_in[10]; const void* h_u_b1   = d_in[11];
  const void* h_u_w2   = d_in[12]; const void* h_u_b2   = d_in[13];
  const void* h_ln_g   = d_in[14]; const void* h_ln_b   = d_in[15];
  const void* h2c_g_w1 = d_in[16]; const void* h2c_g_b1 = d_in[17];
  const void* h2c_g_w2 = d_in[18]; const void* h2c_g_b2 = d_in[19];
  const void* h2c_m_w  = d_in[20]; const void* h2c_m_b  = d_in[21];
  const void* c_u_w1   = d_in[22]; const void* c_u_b1   = d_in[23];
  const void* c_u_w2   = d_in[24]; const void* c_u_b2   = d_in[25];
  const void* c_ln_g   = d_in[26]; const void* c_ln_b   = d_in[27];

  const size_t aggBytes = (size_t)NNODES * HH * sizeof(float);  // 51.2 MB
  float* agg = (float*)d_ws;
  int* flag  = (int*)((char*)d_ws + aggBytes);

  // out offsets: element index NNODES*HH regardless of dtype; byte width differs.
  // We pass raw base pointers and compute element offsets inside (hb), so for the
  // second output we need a dtype-specific base. Handle by passing both possible
  // bases to the variant that uses them.
  void* out_hidden_f32 = d_out;
  void* out_hidden_bf  = d_out;
  void* out_clue_f32 = (void*)((float*)d_out + (size_t)NNODES * HH);
  void* out_clue_bf  = (void*)((u16*)d_out + (size_t)NNODES * HH);

  dtype_probe<<<1, 1, 0, stream>>>((const u32*)h_ln_g, flag);

  // ---- Phase 1: clue -> hidden
  hipMemsetAsync(agg, 0, aggBytes, stream);
  edge_msgs<0><<<256, 1024, 0, stream>>>(flag, h_clue, edges, eattr,
      c2h_g_w1, c2h_g_b1, c2h_g_w2, c2h_g_b2, c2h_m_w, c2h_m_b, agg, 0);
  edge_msgs<1><<<256, 1024, 0, stream>>>(flag, h_clue, edges, eattr,
      c2h_g_w1, c2h_g_b1, c2h_g_w2, c2h_g_b2, c2h_m_w, c2h_m_b, agg, 0);
  node_upd<0><<<256, 1024, 0, stream>>>(flag, h_hidden, agg,
      h_u_w1, h_u_b1, h_u_w2, h_u_b2, h_ln_g, h_ln_b, out_hidden_f32);
  node_upd<1><<<256, 1024, 0, stream>>>(flag, h_hidden, agg,
      h_u_w1, h_u_b1, h_u_w2, h_u_b2, h_ln_g, h_ln_b, out_hidden_bf);

  // ---- Phase 2: hidden_new -> clue
  hipMemsetAsync(agg, 0, aggBytes, stream);
  edge_msgs<0><<<256, 1024, 0, stream>>>(flag, out_hidden_f32, edges, eattr,
      h2c_g_w1, h2c_g_b1, h2c_g_w2, h2c_g_b2, h2c_m_w, h2c_m_b, agg, 1);
  edge_msgs<1><<<256, 1024, 0, stream>>>(flag, out_hidden_bf, edges, eattr,
      h2c_g_w1, h2c_g_b1, h2c_g_w2, h2c_g_b2, h2c_m_w, h2c_m_b, agg, 1);
  node_upd<0><<<256, 1024, 0, stream>>>(flag, h_clue, agg,
      c_u_w1, c_u_b1, c_u_w2, c_u_b2, c_ln_g, c_ln_b, out_clue_f32);
  node_upd<1><<<256, 1024, 0, stream>>>(flag, h_clue, agg,
      c_u_w1, c_u_b1, c_u_w2, c_u_b2, c_ln_g, c_ln_b, out_clue_bf);
}

// Round 7
// 2591.240 us; speedup vs baseline: 1.9097x; 1.9097x over previous
//
#include <hip/hip_runtime.h>

#define HH 128
#define EAA 16
#define NNODES 100000
#define NEDGES 500000
#define NBATCH (NEDGES / 16)   // 31250 exact
#define NNB    (NNODES / 16)   // 6250 exact

#define LDW1 168   // edge w1t row stride: 144 -> 168 (pad read by kt=4, zeroed)
#define LDW2 136   // edge w2t/mwt row stride: 128 + 8
#define LDN1 264   // node w1t row stride: 256 + 8
#define LDN2 136   // node w2t row stride: 128 + 8
#define NW 8       // waves per block

typedef unsigned int u32;
typedef unsigned short u16;
typedef __attribute__((ext_vector_type(8))) short bf16x8;
typedef __attribute__((ext_vector_type(4))) float f32x4;

__device__ __forceinline__ u16 f2bf(float f){
  u32 x = __builtin_bit_cast(u32, f);
  return (u16)((x + 0x7fffu + ((x >> 16) & 1u)) >> 16);
}
__device__ __forceinline__ float sigm(float x){ return 1.0f / (1.0f + __expf(-x)); }
__device__ __forceinline__ uint2 shfl64(uint2 v, int src){
  uint2 r;
  r.x = (u32)__shfl((int)v.x, src, 64);
  r.y = (u32)__shfl((int)v.y, src, 64);
  return r;
}
// pack 8 consecutive f32 at p into a bf16x8 fragment (RNE)
__device__ __forceinline__ bf16x8 ld8f_bf(const float* p){
  float4 v0 = *(const float4*)(p);
  float4 v1 = *(const float4*)(p + 4);
  uint4 u;
  u.x = ((u32)f2bf(v0.y) << 16) | f2bf(v0.x);
  u.y = ((u32)f2bf(v0.w) << 16) | f2bf(v0.z);
  u.z = ((u32)f2bf(v1.y) << 16) | f2bf(v1.x);
  u.w = ((u32)f2bf(v1.w) << 16) | f2bf(v1.z);
  return __builtin_bit_cast(bf16x8, u);
}

// ---------------------------------------------------------------------------
// MFMA edge kernel, 16 edges/wave, f32 I/O, bf16 fragments, f32 accumulate.
//   y^T = silu(w1^T @ cat^T + b1); g^T = w2^T @ y^T + b2; m^T = mw^T @ src^T + mb
//   agg[dst] += m * sigmoid(g)     (f32 atomics)
// Fragment layouts (mfma_f32_16x16x32_bf16):
//   A: lane l holds A[row=l&15][k=(l>>4)*8+i]
//   B: lane l holds B[k=(l>>4)*8+i][col=l&15]
//   D: lane l holds D[row=(l>>4)*4+j][col=l&15]
// Stage-1 D->B redistribution via shuffles: lane (q,er) pulls packed pairs
// from lanes srcA=(2(q&1))*16+er, srcB=srcA+16, tile 2kt+(q>>1).
// ---------------------------------------------------------------------------
__global__ __launch_bounds__(512) void edge_mfma(
    const float* __restrict__ srcN, const int* __restrict__ edges,
    const float* __restrict__ eattr,
    const float* __restrict__ w1, const float* __restrict__ b1,
    const float* __restrict__ w2, const float* __restrict__ b2,
    const float* __restrict__ mw, const float* __restrict__ mb,
    float* __restrict__ agg, int srcCol)
{
  __shared__ alignas(16) u16 w1t[128 * LDW1];        // 43008 B
  __shared__ alignas(16) u16 w2t[128 * LDW2];        // 34816 B
  __shared__ alignas(16) u16 mwt[128 * LDW2];        // 34816 B
  __shared__ float b1s[HH], b2s[HH], mbs[HH];        //  1536 B => 114176 B

  const int tid = threadIdx.x;
  // w1 [144][128] f32 row-major -> w1t[f][k] bf16 transposed
  for (int i = tid; i < 144 * 128; i += 512) {
    int k = i >> 7, f = i & 127;
    w1t[f * LDW1 + k] = f2bf(w1[i]);
  }
  // zero pad k in [144,168): kt=4 MFMA reads k up to 160 for q>=2; 0*NaN hazard
  for (int i = tid; i < 128 * (LDW1 - 144); i += 512) {
    int f = i / (LDW1 - 144), k = 144 + i % (LDW1 - 144);
    w1t[f * LDW1 + k] = 0;
  }
  for (int i = tid; i < 128 * 128; i += 512) {
    int k = i >> 7, f = i & 127;
    w2t[f * LDW2 + k] = f2bf(w2[i]);
    mwt[f * LDW2 + k] = f2bf(mw[i]);
  }
  if (tid < HH) { b1s[tid] = b1[tid]; b2s[tid] = b2[tid]; mbs[tid] = mb[tid]; }
  __syncthreads();

  const int lane = tid & 63;
  const int wid  = tid >> 6;
  const int q    = lane >> 4;
  const int er   = lane & 15;
  const int gw   = blockIdx.x * NW + wid;
  const int nwv  = gridDim.x * NW;
  const int srcA = 2 * (q & 1) * 16 + er;
  const int srcB = srcA + 16;
  const bool hiT = (q >> 1) != 0;

  for (int b = gw; b < NBATCH; b += nwv) {
    const int e0 = b * 16;
    int2 ep = ((const int2*)edges)[e0 + er];
    const int s = srcCol ? ep.y : ep.x;
    const int d = srcCol ? ep.x : ep.y;

    // B-frags from f32 src vector + eattr tail
    bf16x8 bs[5];
    const float* sp = srcN + (size_t)s * HH + q * 8;
    bs[0] = ld8f_bf(sp);
    bs[1] = ld8f_bf(sp + 32);
    bs[2] = ld8f_bf(sp + 64);
    bs[3] = ld8f_bf(sp + 96);
    if (q < 2) bs[4] = ld8f_bf(eattr + (size_t)(e0 + er) * EAA + q * 8);
    else       bs[4] = (bf16x8){0,0,0,0,0,0,0,0};

    // ---- stage 1: y^T tiles + SiLU, packed bf16 pairs in registers
    uint2 pku[8];
#pragma unroll
    for (int t = 0; t < 8; t++) {
      const u16* ap = w1t + (t * 16 + er) * LDW1 + q * 8;
      f32x4 acc = {b1s[t*16 + q*4 + 0], b1s[t*16 + q*4 + 1],
                   b1s[t*16 + q*4 + 2], b1s[t*16 + q*4 + 3]};
#pragma unroll
      for (int kt = 0; kt < 5; kt++) {
        bf16x8 af = *(const bf16x8*)(ap + kt * 32);
        acc = __builtin_amdgcn_mfma_f32_16x16x32_bf16(af, bs[kt], acc, 0, 0, 0);
      }
      float v0 = acc[0] * sigm(acc[0]), v1 = acc[1] * sigm(acc[1]);
      float v2 = acc[2] * sigm(acc[2]), v3 = acc[3] * sigm(acc[3]);
      pku[t].x = ((u32)f2bf(v1) << 16) | f2bf(v0);
      pku[t].y = ((u32)f2bf(v3) << 16) | f2bf(v2);
    }

    // ---- redistribute y (D-layout -> B-frag) via shuffles
    bf16x8 yb[4];
#pragma unroll
    for (int kt = 0; kt < 4; kt++) {
      uint2 aLo = shfl64(pku[2*kt],     srcA);
      uint2 aHi = shfl64(pku[2*kt + 1], srcA);
      uint2 bLo = shfl64(pku[2*kt],     srcB);
      uint2 bHi = shfl64(pku[2*kt + 1], srcB);
      uint4 w;
      w.x = hiT ? aHi.x : aLo.x;
      w.y = hiT ? aHi.y : aLo.y;
      w.z = hiT ? bHi.x : bLo.x;
      w.w = hiT ? bHi.y : bLo.y;
      yb[kt] = __builtin_bit_cast(bf16x8, w);
    }

    // ---- stage 2+3: gate and message, fused; scatter f32 atomics
#pragma unroll
    for (int t = 0; t < 8; t++) {
      const u16* ap2 = w2t + (t * 16 + er) * LDW2 + q * 8;
      const u16* ap3 = mwt + (t * 16 + er) * LDW2 + q * 8;
      f32x4 g = {b2s[t*16 + q*4 + 0], b2s[t*16 + q*4 + 1],
                 b2s[t*16 + q*4 + 2], b2s[t*16 + q*4 + 3]};
      f32x4 m = {mbs[t*16 + q*4 + 0], mbs[t*16 + q*4 + 1],
                 mbs[t*16 + q*4 + 2], mbs[t*16 + q*4 + 3]};
#pragma unroll
      for (int kt = 0; kt < 4; kt++) {
        bf16x8 a2 = *(const bf16x8*)(ap2 + kt * 32);
        g = __builtin_amdgcn_mfma_f32_16x16x32_bf16(a2, yb[kt], g, 0, 0, 0);
        bf16x8 a3 = *(const bf16x8*)(ap3 + kt * 32);
        m = __builtin_amdgcn_mfma_f32_16x16x32_bf16(a3, bs[kt], m, 0, 0, 0);
      }
      float* dst = agg + (size_t)d * HH + t * 16 + q * 4;
      atomicAdd(dst + 0, m[0] * sigm(g[0]));
      atomicAdd(dst + 1, m[1] * sigm(g[1]));
      atomicAdd(dst + 2, m[2] * sigm(g[2]));
      atomicAdd(dst + 3, m[3] * sigm(g[3]));
    }
  }
}

// ---------------------------------------------------------------------------
// MFMA node update, 16 nodes/wave, f32 I/O:
//   u^T = relu(w1^T @ [hin,agg]^T + b1); upd^T = w2^T @ u^T + b2
//   out = LN(hin + upd) * g + b        (LN in f32, out stored f32)
// ---------------------------------------------------------------------------
__global__ __launch_bounds__(512) void node_mfma(
    const float* __restrict__ hin, const float* __restrict__ agg,
    const float* __restrict__ w1, const float* __restrict__ b1,
    const float* __restrict__ w2, const float* __restrict__ b2,
    const float* __restrict__ lng, const float* __restrict__ lnb,
    float* __restrict__ out)
{
  __shared__ alignas(16) u16 w1t[128 * LDN1];   // 67584 B
  __shared__ alignas(16) u16 w2t[128 * LDN2];   // 34816 B
  __shared__ float b1s[HH], b2s[HH], gsv[HH], bsv[HH];  // 2048 B => 104448 B

  const int tid = threadIdx.x;
  // w1 [256][128] f32 -> w1t[f][k] bf16 transposed
  for (int i = tid; i < 256 * 128; i += 512) {
    int k = i >> 7, f = i & 127;
    w1t[f * LDN1 + k] = f2bf(w1[i]);
  }
  for (int i = tid; i < 128 * 128; i += 512) {
    int k = i >> 7, f = i & 127;
    w2t[f * LDN2 + k] = f2bf(w2[i]);
  }
  if (tid < HH) { b1s[tid] = b1[tid]; b2s[tid] = b2[tid];
                  gsv[tid] = lng[tid]; bsv[tid] = lnb[tid]; }
  __syncthreads();

  const int lane = tid & 63;
  const int wid  = tid >> 6;
  const int q    = lane >> 4;
  const int nr   = lane & 15;
  const int gw   = blockIdx.x * NW + wid;
  const int nwv  = gridDim.x * NW;
  const int srcA = 2 * (q & 1) * 16 + nr;
  const int srcB = srcA + 16;
  const bool hiT = (q >> 1) != 0;

  for (int nb = gw; nb < NNB; nb += nwv) {
    const int n = nb * 16 + nr;
    const size_t base = (size_t)n * HH;

    // B-frags: cat = [hin | agg], both f32
    bf16x8 cb[8];
    const float* hp = hin + base + q * 8;
    cb[0] = ld8f_bf(hp);
    cb[1] = ld8f_bf(hp + 32);
    cb[2] = ld8f_bf(hp + 64);
    cb[3] = ld8f_bf(hp + 96);
    const float* ap = agg + base + q * 8;
    cb[4] = ld8f_bf(ap);
    cb[5] = ld8f_bf(ap + 32);
    cb[6] = ld8f_bf(ap + 64);
    cb[7] = ld8f_bf(ap + 96);

    // ---- stage 1: u^T = relu(w1^T @ cat^T + b1)
    uint2 pku[8];
#pragma unroll
    for (int t = 0; t < 8; t++) {
      const u16* a1p = w1t + (t * 16 + nr) * LDN1 + q * 8;
      f32x4 acc = {b1s[t*16 + q*4 + 0], b1s[t*16 + q*4 + 1],
                   b1s[t*16 + q*4 + 2], b1s[t*16 + q*4 + 3]};
#pragma unroll
      for (int kt = 0; kt < 8; kt++) {
        bf16x8 af = *(const bf16x8*)(a1p + kt * 32);
        acc = __builtin_amdgcn_mfma_f32_16x16x32_bf16(af, cb[kt], acc, 0, 0, 0);
      }
      float v0 = fmaxf(acc[0], 0.0f), v1 = fmaxf(acc[1], 0.0f);
      float v2 = fmaxf(acc[2], 0.0f), v3 = fmaxf(acc[3], 0.0f);
      pku[t].x = ((u32)f2bf(v1) << 16) | f2bf(v0);
      pku[t].y = ((u32)f2bf(v3) << 16) | f2bf(v2);
    }

    // ---- redistribute u (D-layout -> B-frag) via shuffles
    bf16x8 yb[4];
#pragma unroll
    for (int kt = 0; kt < 4; kt++) {
      uint2 aLo = shfl64(pku[2*kt],     srcA);
      uint2 aHi = shfl64(pku[2*kt + 1], srcA);
      uint2 bLo = shfl64(pku[2*kt],     srcB);
      uint2 bHi = shfl64(pku[2*kt + 1], srcB);
      uint4 w;
      w.x = hiT ? aHi.x : aLo.x;
      w.y = hiT ? aHi.y : aLo.y;
      w.z = hiT ? bHi.x : bLo.x;
      w.w = hiT ? bHi.y : bLo.y;
      yb[kt] = __builtin_bit_cast(bf16x8, w);
    }

    // ---- stage 2: upd + residual + layernorm (f32)
    float xv[8][4];
    float psum = 0.0f;
#pragma unroll
    for (int t = 0; t < 8; t++) {
      const u16* a2p = w2t + (t * 16 + nr) * LDN2 + q * 8;
      f32x4 uacc = {b2s[t*16 + q*4 + 0], b2s[t*16 + q*4 + 1],
                    b2s[t*16 + q*4 + 2], b2s[t*16 + q*4 + 3]};
#pragma unroll
      for (int kt = 0; kt < 4; kt++) {
        bf16x8 a2 = *(const bf16x8*)(a2p + kt * 32);
        uacc = __builtin_amdgcn_mfma_f32_16x16x32_bf16(a2, yb[kt], uacc, 0, 0, 0);
      }
      float4 hv = *(const float4*)(hin + base + t * 16 + q * 4);
      xv[t][0] = hv.x + uacc[0];
      xv[t][1] = hv.y + uacc[1];
      xv[t][2] = hv.z + uacc[2];
      xv[t][3] = hv.w + uacc[3];
      psum += xv[t][0] + xv[t][1] + xv[t][2] + xv[t][3];
    }
    psum += __shfl_xor(psum, 16, 64);
    psum += __shfl_xor(psum, 32, 64);
    float mu = psum * (1.0f / 128.0f);
    float pvar = 0.0f;
#pragma unroll
    for (int t = 0; t < 8; t++) {
#pragma unroll
      for (int j = 0; j < 4; j++) {
        float dx = xv[t][j] - mu;
        xv[t][j] = dx;
        pvar += dx * dx;
      }
    }
    pvar += __shfl_xor(pvar, 16, 64);
    pvar += __shfl_xor(pvar, 32, 64);
    float inv = rsqrtf(pvar * (1.0f / 128.0f) + 1e-5f);
#pragma unroll
    for (int t = 0; t < 8; t++) {
      int F = t * 16 + q * 4;
      float4 ov;
      ov.x = xv[t][0] * inv * gsv[F + 0] + bsv[F + 0];
      ov.y = xv[t][1] * inv * gsv[F + 1] + bsv[F + 1];
      ov.z = xv[t][2] * inv * gsv[F + 2] + bsv[F + 2];
      ov.w = xv[t][3] * inv * gsv[F + 3] + bsv[F + 3];
      *(float4*)(out + base + F) = ov;
    }
  }
}

extern "C" void kernel_launch(void* const* d_in, const int* in_sizes, int n_in,
                              void* d_out, int out_size, void* d_ws, size_t ws_size,
                              hipStream_t stream) {
  const float* h_hidden = (const float*)d_in[0];
  const float* h_clue   = (const float*)d_in[1];
  const int*   edges    = (const int*)d_in[2];
  const float* eattr    = (const float*)d_in[3];
  const float* c2h_g_w1 = (const float*)d_in[4];  const float* c2h_g_b1 = (const float*)d_in[5];
  const float* c2h_g_w2 = (const float*)d_in[6];  const float* c2h_g_b2 = (const float*)d_in[7];
  const float* c2h_m_w  = (const float*)d_in[8];  const float* c2h_m_b  = (const float*)d_in[9];
  const float* h_u_w1   = (const float*)d_in[10]; const float* h_u_b1   = (const float*)d_in[11];
  const float* h_u_w2   = (const float*)d_in[12]; const float* h_u_b2   = (const float*)d_in[13];
  const float* h_ln_g   = (const float*)d_in[14]; const float* h_ln_b   = (const float*)d_in[15];
  const float* h2c_g_w1 = (const float*)d_in[16]; const float* h2c_g_b1 = (const float*)d_in[17];
  const float* h2c_g_w2 = (const float*)d_in[18]; const float* h2c_g_b2 = (const float*)d_in[19];
  const float* h2c_m_w  = (const float*)d_in[20]; const float* h2c_m_b  = (const float*)d_in[21];
  const float* c_u_w1   = (const float*)d_in[22]; const float* c_u_b1   = (const float*)d_in[23];
  const float* c_u_w2   = (const float*)d_in[24]; const float* c_u_b2   = (const float*)d_in[25];
  const float* c_ln_g   = (const float*)d_in[26]; const float* c_ln_b   = (const float*)d_in[27];

  float* out_hidden = (float*)d_out;
  float* out_clue   = (float*)d_out + (size_t)NNODES * HH;
  float* agg = (float*)d_ws;
  const size_t aggBytes = (size_t)NNODES * HH * sizeof(float);  // 51.2 MB

  // Phase 1: clue -> hidden (src = edges[:,0], dst = edges[:,1])
  hipMemsetAsync(agg, 0, aggBytes, stream);
  edge_mfma<<<256, 512, 0, stream>>>(h_clue, edges, eattr,
      c2h_g_w1, c2h_g_b1, c2h_g_w2, c2h_g_b2, c2h_m_w, c2h_m_b, agg, 0);
  node_mfma<<<256, 512, 0, stream>>>(h_hidden, agg,
      h_u_w1, h_u_b1, h_u_w2, h_u_b2, h_ln_g, h_ln_b, out_hidden);

  // Phase 2: hidden_new -> clue (src = edges[:,1], dst = edges[:,0])
  hipMemsetAsync(agg, 0, aggBytes, stream);
  edge_mfma<<<256, 512, 0, stream>>>(out_hidden, edges, eattr,
      h2c_g_w1, h2c_g_b1, h2c_g_w2, h2c_g_b2, h2c_m_w, h2c_m_b, agg, 1);
  node_mfma<<<256, 512, 0, stream>>>(h_clue, agg,
      c_u_w1, c_u_b1, c_u_w2, c_u_b2, c_ln_g, c_ln_b, out_clue);
}

// Round 8
// 2200.885 us; speedup vs baseline: 2.2484x; 1.1774x over previous
//
#include <hip/hip_runtime.h>

#define HH 128
#define EAA 16
#define NNODES 100000
#define NEDGES 500000
#define NBATCH (NEDGES / 16)   // 31250 exact
#define NNB    (NNODES / 16)   // 6250 exact
#define CHUNK 512
#define NCHUNK ((NNODES + CHUNK - 1) / CHUNK)  // 196

// fallback (round-7) LDS strides
#define LDW1 168
#define LDW2 136
#define LDN1 264
#define LDN2 136
#define NW 8

// global transposed-weight row strides (elements, 16B-multiple)
#define GE1 160   // edge w1t: k in [0,160), real 144, pad zeroed
#define GE2 128
#define GN1 256
#define GN2 128

typedef unsigned int u32;
typedef unsigned short u16;
typedef __attribute__((ext_vector_type(8))) short bf16x8;
typedef __attribute__((ext_vector_type(4))) float f32x4;

__device__ __forceinline__ float bf_lo(u32 v){ return __builtin_bit_cast(float, (u32)(v << 16)); }
__device__ __forceinline__ float bf_hi(u32 v){ return __builtin_bit_cast(float, (u32)(v & 0xffff0000u)); }
__device__ __forceinline__ u16 f2bf(float f){
  u32 x = __builtin_bit_cast(u32, f);
  return (u16)((x + 0x7fffu + ((x >> 16) & 1u)) >> 16);
}
__device__ __forceinline__ float sigm(float x){ return 1.0f / (1.0f + __expf(-x)); }
__device__ __forceinline__ uint2 shfl64(uint2 v, int src){
  uint2 r;
  r.x = (u32)__shfl((int)v.x, src, 64);
  r.y = (u32)__shfl((int)v.y, src, 64);
  return r;
}
__device__ __forceinline__ bf16x8 ld8f_bf(const float* p){
  float4 v0 = *(const float4*)(p);
  float4 v1 = *(const float4*)(p + 4);
  uint4 u;
  u.x = ((u32)f2bf(v0.y) << 16) | f2bf(v0.x);
  u.y = ((u32)f2bf(v0.w) << 16) | f2bf(v0.z);
  u.z = ((u32)f2bf(v1.y) << 16) | f2bf(v1.x);
  u.w = ((u32)f2bf(v1.w) << 16) | f2bf(v1.z);
  return __builtin_bit_cast(bf16x8, u);
}

// ===========================================================================
// Weight staging: transpose f32 [K][128] -> bf16 [128][Kpad] (zero pad).
// 5 matrices per phase in one launch (blockIdx.y selects).
// ===========================================================================
__global__ void stage_weights(
    const float* __restrict__ w1e, const float* __restrict__ w2e, const float* __restrict__ mwe,
    const float* __restrict__ w1n, const float* __restrict__ w2n,
    u16* __restrict__ gw1e, u16* __restrict__ gw2e, u16* __restrict__ gmwe,
    u16* __restrict__ gw1n, u16* __restrict__ gw2n)
{
  const float* src; u16* dst; int K, KP;
  switch (blockIdx.y) {
    case 0: src = w1e; dst = gw1e; K = 144; KP = GE1; break;
    case 1: src = w2e; dst = gw2e; K = 128; KP = GE2; break;
    case 2: src = mwe; dst = gmwe; K = 128; KP = GE2; break;
    case 3: src = w1n; dst = gw1n; K = 256; KP = GN1; break;
    default: src = w2n; dst = gw2n; K = 128; KP = GN2; break;
  }
  int total = 128 * KP;
  for (int i = blockIdx.x * blockDim.x + threadIdx.x; i < total; i += gridDim.x * blockDim.x) {
    int f = i / KP, k = i - f * KP;
    dst[i] = (k < K) ? f2bf(src[(size_t)k * 128 + f]) : (u16)0;
  }
}

// ===========================================================================
// CSR build: count -> 3-kernel exclusive scan -> fill
// ===========================================================================
__global__ void count_k(const int* __restrict__ edges, int col, int* __restrict__ cnt){
  int e = blockIdx.x * blockDim.x + threadIdx.x;
  if (e < NEDGES) atomicAdd(&cnt[edges[2 * e + col]], 1);
}
__global__ void scanA_k(const int* __restrict__ cnt, int* __restrict__ off, int* __restrict__ csum){
  __shared__ int ws[8];
  int i = blockIdx.x * CHUNK + threadIdx.x;
  int v = (i < NNODES) ? cnt[i] : 0;
  int lane = threadIdx.x & 63, w = threadIdx.x >> 6;
  int s = v;
#pragma unroll
  for (int d = 1; d < 64; d <<= 1){ int t = __shfl_up(s, d, 64); if (lane >= d) s += t; }
  if (lane == 63) ws[w] = s;
  __syncthreads();
  if (threadIdx.x == 0){
    int a = 0;
    for (int k = 0; k < 8; k++){ int t = ws[k]; ws[k] = a; a += t; }
    csum[blockIdx.x] = a;
  }
  __syncthreads();
  if (i < NNODES) off[i] = (s - v) + ws[w];
}
__global__ void scanB_k(int* __restrict__ csum){
  if (threadIdx.x == 0 && blockIdx.x == 0){
    int a = 0;
    for (int k = 0; k < NCHUNK; k++){ int t = csum[k]; csum[k] = a; a += t; }
  }
}
__global__ void scanC_k(int* __restrict__ off, int* __restrict__ pos, const int* __restrict__ csum){
  int i = blockIdx.x * blockDim.x + threadIdx.x;
  if (i < NNODES){ int v = off[i] + csum[i / CHUNK]; off[i] = v; pos[i] = v; }
  if (i == 0) off[NNODES] = NEDGES;
}
__global__ void fill_k(const int* __restrict__ edges, int col, int* __restrict__ pos, int* __restrict__ elist){
  int e = blockIdx.x * blockDim.x + threadIdx.x;
  if (e < NEDGES){ int d = edges[2 * e + col]; int p = atomicAdd(&pos[d], 1); elist[p] = e; }
}

// ===========================================================================
// Edge message kernel (NO atomics, NO weight LDS). 16 edges/wave.
// Writes msgs[e][0..128) bf16.
// ===========================================================================
__global__ __launch_bounds__(512, 2) void edge_msg_w(
    const float* __restrict__ srcN, const int* __restrict__ edges,
    const float* __restrict__ eattr,
    const u16* __restrict__ w1t, const float* __restrict__ b1,
    const u16* __restrict__ w2t, const float* __restrict__ b2,
    const u16* __restrict__ mwt, const float* __restrict__ mb,
    u16* __restrict__ msgs, int srcCol)
{
  __shared__ float b1s[HH], b2s[HH], mbs[HH];
  const int tid = threadIdx.x;
  if (tid < HH){ b1s[tid] = b1[tid]; b2s[tid] = b2[tid]; mbs[tid] = mb[tid]; }
  __syncthreads();

  const int lane = tid & 63;
  const int wid  = tid >> 6;
  const int q    = lane >> 4;
  const int er   = lane & 15;
  const int gw   = blockIdx.x * NW + wid;
  const int nwv  = gridDim.x * NW;
  const int srcA = 2 * (q & 1) * 16 + er;
  const int srcB = srcA + 16;
  const bool hiT = (q >> 1) != 0;

  for (int b = gw; b < NBATCH; b += nwv) {
    const int e0 = b * 16;
    int2 ep = ((const int2*)edges)[e0 + er];
    const int s = srcCol ? ep.y : ep.x;

    bf16x8 bs[5];
    const float* sp = srcN + (size_t)s * HH + q * 8;
    bs[0] = ld8f_bf(sp);
    bs[1] = ld8f_bf(sp + 32);
    bs[2] = ld8f_bf(sp + 64);
    bs[3] = ld8f_bf(sp + 96);
    if (q < 2) bs[4] = ld8f_bf(eattr + (size_t)(e0 + er) * EAA + q * 8);
    else       bs[4] = (bf16x8){0,0,0,0,0,0,0,0};

    // stage 1: y^T + SiLU
    uint2 pku[8];
#pragma unroll
    for (int t = 0; t < 8; t++) {
      const u16* ap = w1t + (size_t)(t * 16 + er) * GE1 + q * 8;
      f32x4 acc = {b1s[t*16 + q*4 + 0], b1s[t*16 + q*4 + 1],
                   b1s[t*16 + q*4 + 2], b1s[t*16 + q*4 + 3]};
#pragma unroll
      for (int kt = 0; kt < 5; kt++) {
        bf16x8 af = *(const bf16x8*)(ap + kt * 32);
        acc = __builtin_amdgcn_mfma_f32_16x16x32_bf16(af, bs[kt], acc, 0, 0, 0);
      }
      float v0 = acc[0] * sigm(acc[0]), v1 = acc[1] * sigm(acc[1]);
      float v2 = acc[2] * sigm(acc[2]), v3 = acc[3] * sigm(acc[3]);
      pku[t].x = ((u32)f2bf(v1) << 16) | f2bf(v0);
      pku[t].y = ((u32)f2bf(v3) << 16) | f2bf(v2);
    }

    // D-layout -> B-frag redistribution (in-register)
    bf16x8 yb[4];
#pragma unroll
    for (int kt = 0; kt < 4; kt++) {
      uint2 aLo = shfl64(pku[2*kt],     srcA);
      uint2 aHi = shfl64(pku[2*kt + 1], srcA);
      uint2 bLo = shfl64(pku[2*kt],     srcB);
      uint2 bHi = shfl64(pku[2*kt + 1], srcB);
      uint4 w;
      w.x = hiT ? aHi.x : aLo.x;
      w.y = hiT ? aHi.y : aLo.y;
      w.z = hiT ? bHi.x : bLo.x;
      w.w = hiT ? bHi.y : bLo.y;
      yb[kt] = __builtin_bit_cast(bf16x8, w);
    }

    // stage 2+3: gate & message, write msg row (bf16)
#pragma unroll
    for (int t = 0; t < 8; t++) {
      const u16* ap2 = w2t + (size_t)(t * 16 + er) * GE2 + q * 8;
      const u16* ap3 = mwt + (size_t)(t * 16 + er) * GE2 + q * 8;
      f32x4 g = {b2s[t*16 + q*4 + 0], b2s[t*16 + q*4 + 1],
                 b2s[t*16 + q*4 + 2], b2s[t*16 + q*4 + 3]};
      f32x4 m = {mbs[t*16 + q*4 + 0], mbs[t*16 + q*4 + 1],
                 mbs[t*16 + q*4 + 2], mbs[t*16 + q*4 + 3]};
#pragma unroll
      for (int kt = 0; kt < 4; kt++) {
        bf16x8 a2 = *(const bf16x8*)(ap2 + kt * 32);
        g = __builtin_amdgcn_mfma_f32_16x16x32_bf16(a2, yb[kt], g, 0, 0, 0);
        bf16x8 a3 = *(const bf16x8*)(ap3 + kt * 32);
        m = __builtin_amdgcn_mfma_f32_16x16x32_bf16(a3, bs[kt], m, 0, 0, 0);
      }
      float v0 = m[0] * sigm(g[0]), v1 = m[1] * sigm(g[1]);
      float v2 = m[2] * sigm(g[2]), v3 = m[3] * sigm(g[3]);
      uint2 pk;
      pk.x = ((u32)f2bf(v1) << 16) | f2bf(v0);
      pk.y = ((u32)f2bf(v3) << 16) | f2bf(v2);
      *(uint2*)(msgs + (size_t)(e0 + er) * HH + t * 16 + q * 4) = pk;
    }
  }
}

// ===========================================================================
// Node update with CSR pull-aggregation (no agg buffer). 16 nodes/wave.
// ===========================================================================
__global__ __launch_bounds__(512, 2) void node_csr(
    const float* __restrict__ hin,
    const u16* __restrict__ msgs, const int* __restrict__ off, const int* __restrict__ elist,
    const u16* __restrict__ w1t, const float* __restrict__ b1,
    const u16* __restrict__ w2t, const float* __restrict__ b2,
    const float* __restrict__ lng, const float* __restrict__ lnb,
    float* __restrict__ out)
{
  __shared__ float b1s[HH], b2s[HH], gsv[HH], bsv[HH];
  const int tid = threadIdx.x;
  if (tid < HH){ b1s[tid] = b1[tid]; b2s[tid] = b2[tid];
                 gsv[tid] = lng[tid]; bsv[tid] = lnb[tid]; }
  __syncthreads();

  const int lane = tid & 63;
  const int wid  = tid >> 6;
  const int q    = lane >> 4;
  const int nr   = lane & 15;
  const int gw   = blockIdx.x * NW + wid;
  const int nwv  = gridDim.x * NW;
  const int srcA = 2 * (q & 1) * 16 + nr;
  const int srcB = srcA + 16;
  const bool hiT = (q >> 1) != 0;

  for (int nb = gw; nb < NNB; nb += nwv) {
    const int n = nb * 16 + nr;
    const size_t base = (size_t)n * HH;

    // ---- pull-aggregate this node's messages (f32 accum in registers)
    float av[32];
#pragma unroll
    for (int j = 0; j < 32; j++) av[j] = 0.0f;
    const int beg = off[n], end = off[n + 1];
    for (int i = 0; ; i++) {
      bool act = (beg + i < end);
      if (!__any(act)) break;
      if (act) {
        int eid = elist[beg + i];
        const u16* mp = msgs + (size_t)eid * HH + q * 8;
#pragma unroll
        for (int kt = 0; kt < 4; kt++) {
          uint4 r = *(const uint4*)(mp + kt * 32);
          av[kt*8+0] += bf_lo(r.x); av[kt*8+1] += bf_hi(r.x);
          av[kt*8+2] += bf_lo(r.y); av[kt*8+3] += bf_hi(r.y);
          av[kt*8+4] += bf_lo(r.z); av[kt*8+5] += bf_hi(r.z);
          av[kt*8+6] += bf_lo(r.w); av[kt*8+7] += bf_hi(r.w);
        }
      }
    }

    // ---- B-frags: cat = [hin | agg]
    bf16x8 cb[8];
    const float* hp = hin + base + q * 8;
    cb[0] = ld8f_bf(hp);
    cb[1] = ld8f_bf(hp + 32);
    cb[2] = ld8f_bf(hp + 64);
    cb[3] = ld8f_bf(hp + 96);
#pragma unroll
    for (int kt = 0; kt < 4; kt++) {
      uint4 u;
      u.x = ((u32)f2bf(av[kt*8+1]) << 16) | f2bf(av[kt*8+0]);
      u.y = ((u32)f2bf(av[kt*8+3]) << 16) | f2bf(av[kt*8+2]);
      u.z = ((u32)f2bf(av[kt*8+5]) << 16) | f2bf(av[kt*8+4]);
      u.w = ((u32)f2bf(av[kt*8+7]) << 16) | f2bf(av[kt*8+6]);
      cb[4 + kt] = __builtin_bit_cast(bf16x8, u);
    }

    // ---- stage 1: u^T = relu(w1^T @ cat^T + b1)
    uint2 pku[8];
#pragma unroll
    for (int t = 0; t < 8; t++) {
      const u16* a1p = w1t + (size_t)(t * 16 + nr) * GN1 + q * 8;
      f32x4 acc = {b1s[t*16 + q*4 + 0], b1s[t*16 + q*4 + 1],
                   b1s[t*16 + q*4 + 2], b1s[t*16 + q*4 + 3]};
#pragma unroll
      for (int kt = 0; kt < 8; kt++) {
        bf16x8 af = *(const bf16x8*)(a1p + kt * 32);
        acc = __builtin_amdgcn_mfma_f32_16x16x32_bf16(af, cb[kt], acc, 0, 0, 0);
      }
      float v0 = fmaxf(acc[0], 0.0f), v1 = fmaxf(acc[1], 0.0f);
      float v2 = fmaxf(acc[2], 0.0f), v3 = fmaxf(acc[3], 0.0f);
      pku[t].x = ((u32)f2bf(v1) << 16) | f2bf(v0);
      pku[t].y = ((u32)f2bf(v3) << 16) | f2bf(v2);
    }

    bf16x8 yb[4];
#pragma unroll
    for (int kt = 0; kt < 4; kt++) {
      uint2 aLo = shfl64(pku[2*kt],     srcA);
      uint2 aHi = shfl64(pku[2*kt + 1], srcA);
      uint2 bLo = shfl64(pku[2*kt],     srcB);
      uint2 bHi = shfl64(pku[2*kt + 1], srcB);
      uint4 w;
      w.x = hiT ? aHi.x : aLo.x;
      w.y = hiT ? aHi.y : aLo.y;
      w.z = hiT ? bHi.x : bLo.x;
      w.w = hiT ? bHi.y : bLo.y;
      yb[kt] = __builtin_bit_cast(bf16x8, w);
    }

    // ---- stage 2 + residual + LN
    float xv[8][4];
    float psum = 0.0f;
#pragma unroll
    for (int t = 0; t < 8; t++) {
      const u16* a2p = w2t + (size_t)(t * 16 + nr) * GN2 + q * 8;
      f32x4 uacc = {b2s[t*16 + q*4 + 0], b2s[t*16 + q*4 + 1],
                    b2s[t*16 + q*4 + 2], b2s[t*16 + q*4 + 3]};
#pragma unroll
      for (int kt = 0; kt < 4; kt++) {
        bf16x8 a2 = *(const bf16x8*)(a2p + kt * 32);
        uacc = __builtin_amdgcn_mfma_f32_16x16x32_bf16(a2, yb[kt], uacc, 0, 0, 0);
      }
      float4 hv = *(const float4*)(hin + base + t * 16 + q * 4);
      xv[t][0] = hv.x + uacc[0];
      xv[t][1] = hv.y + uacc[1];
      xv[t][2] = hv.z + uacc[2];
      xv[t][3] = hv.w + uacc[3];
      psum += xv[t][0] + xv[t][1] + xv[t][2] + xv[t][3];
    }
    psum += __shfl_xor(psum, 16, 64);
    psum += __shfl_xor(psum, 32, 64);
    float mu = psum * (1.0f / 128.0f);
    float pvar = 0.0f;
#pragma unroll
    for (int t = 0; t < 8; t++) {
#pragma unroll
      for (int j = 0; j < 4; j++) {
        float dx = xv[t][j] - mu;
        xv[t][j] = dx;
        pvar += dx * dx;
      }
    }
    pvar += __shfl_xor(pvar, 16, 64);
    pvar += __shfl_xor(pvar, 32, 64);
    float inv = rsqrtf(pvar * (1.0f / 128.0f) + 1e-5f);
#pragma unroll
    for (int t = 0; t < 8; t++) {
      int F = t * 16 + q * 4;
      float4 ov;
      ov.x = xv[t][0] * inv * gsv[F + 0] + bsv[F + 0];
      ov.y = xv[t][1] * inv * gsv[F + 1] + bsv[F + 1];
      ov.z = xv[t][2] * inv * gsv[F + 2] + bsv[F + 2];
      ov.w = xv[t][3] * inv * gsv[F + 3] + bsv[F + 3];
      *(float4*)(out + base + F) = ov;
    }
  }
}

// ===========================================================================
// FALLBACK (round-7 verified): LDS-staged MFMA edge kernel with f32 atomics
// ===========================================================================
__global__ __launch_bounds__(512) void edge_mfma(
    const float* __restrict__ srcN, const int* __restrict__ edges,
    const float* __restrict__ eattr,
    const float* __restrict__ w1, const float* __restrict__ b1,
    const float* __restrict__ w2, const float* __restrict__ b2,
    const float* __restrict__ mw, const float* __restrict__ mb,
    float* __restrict__ agg, int srcCol)
{
  __shared__ alignas(16) u16 w1t[128 * LDW1];
  __shared__ alignas(16) u16 w2t[128 * LDW2];
  __shared__ alignas(16) u16 mwt[128 * LDW2];
  __shared__ float b1s[HH], b2s[HH], mbs[HH];

  const int tid = threadIdx.x;
  for (int i = tid; i < 144 * 128; i += 512) {
    int k = i >> 7, f = i & 127;
    w1t[f * LDW1 + k] = f2bf(w1[i]);
  }
  for (int i = tid; i < 128 * (LDW1 - 144); i += 512) {
    int f = i / (LDW1 - 144), k = 144 + i % (LDW1 - 144);
    w1t[f * LDW1 + k] = 0;
  }
  for (int i = tid; i < 128 * 128; i += 512) {
    int k = i >> 7, f = i & 127;
    w2t[f * LDW2 + k] = f2bf(w2[i]);
    mwt[f * LDW2 + k] = f2bf(mw[i]);
  }
  if (tid < HH) { b1s[tid] = b1[tid]; b2s[tid] = b2[tid]; mbs[tid] = mb[tid]; }
  __syncthreads();

  const int lane = tid & 63;
  const int wid  = tid >> 6;
  const int q    = lane >> 4;
  const int er   = lane & 15;
  const int gw   = blockIdx.x * NW + wid;
  const int nwv  = gridDim.x * NW;
  const int srcA = 2 * (q & 1) * 16 + er;
  const int srcB = srcA + 16;
  const bool hiT = (q >> 1) != 0;

  for (int b = gw; b < NBATCH; b += nwv) {
    const int e0 = b * 16;
    int2 ep = ((const int2*)edges)[e0 + er];
    const int s = srcCol ? ep.y : ep.x;
    const int d = srcCol ? ep.x : ep.y;

    bf16x8 bs[5];
    const float* sp = srcN + (size_t)s * HH + q * 8;
    bs[0] = ld8f_bf(sp);
    bs[1] = ld8f_bf(sp + 32);
    bs[2] = ld8f_bf(sp + 64);
    bs[3] = ld8f_bf(sp + 96);
    if (q < 2) bs[4] = ld8f_bf(eattr + (size_t)(e0 + er) * EAA + q * 8);
    else       bs[4] = (bf16x8){0,0,0,0,0,0,0,0};

    uint2 pku[8];
#pragma unroll
    for (int t = 0; t < 8; t++) {
      const u16* ap = w1t + (t * 16 + er) * LDW1 + q * 8;
      f32x4 acc = {b1s[t*16 + q*4 + 0], b1s[t*16 + q*4 + 1],
                   b1s[t*16 + q*4 + 2], b1s[t*16 + q*4 + 3]};
#pragma unroll
      for (int kt = 0; kt < 5; kt++) {
        bf16x8 af = *(const bf16x8*)(ap + kt * 32);
        acc = __builtin_amdgcn_mfma_f32_16x16x32_bf16(af, bs[kt], acc, 0, 0, 0);
      }
      float v0 = acc[0] * sigm(acc[0]), v1 = acc[1] * sigm(acc[1]);
      float v2 = acc[2] * sigm(acc[2]), v3 = acc[3] * sigm(acc[3]);
      pku[t].x = ((u32)f2bf(v1) << 16) | f2bf(v0);
      pku[t].y = ((u32)f2bf(v3) << 16) | f2bf(v2);
    }

    bf16x8 yb[4];
#pragma unroll
    for (int kt = 0; kt < 4; kt++) {
      uint2 aLo = shfl64(pku[2*kt],     srcA);
      uint2 aHi = shfl64(pku[2*kt + 1], srcA);
      uint2 bLo = shfl64(pku[2*kt],     srcB);
      uint2 bHi = shfl64(pku[2*kt + 1], srcB);
      uint4 w;
      w.x = hiT ? aHi.x : aLo.x;
      w.y = hiT ? aHi.y : aLo.y;
      w.z = hiT ? bHi.x : bLo.x;
      w.w = hiT ? bHi.y : bLo.y;
      yb[kt] = __builtin_bit_cast(bf16x8, w);
    }

#pragma unroll
    for (int t = 0; t < 8; t++) {
      const u16* ap2 = w2t + (t * 16 + er) * LDW2 + q * 8;
      const u16* ap3 = mwt + (t * 16 + er) * LDW2 + q * 8;
      f32x4 g = {b2s[t*16 + q*4 + 0], b2s[t*16 + q*4 + 1],
                 b2s[t*16 + q*4 + 2], b2s[t*16 + q*4 + 3]};
      f32x4 m = {mbs[t*16 + q*4 + 0], mbs[t*16 + q*4 + 1],
                 mbs[t*16 + q*4 + 2], mbs[t*16 + q*4 + 3]};
#pragma unroll
      for (int kt = 0; kt < 4; kt++) {
        bf16x8 a2 = *(const bf16x8*)(ap2 + kt * 32);
        g = __builtin_amdgcn_mfma_f32_16x16x32_bf16(a2, yb[kt], g, 0, 0, 0);
        bf16x8 a3 = *(const bf16x8*)(ap3 + kt * 32);
        m = __builtin_amdgcn_mfma_f32_16x16x32_bf16(a3, bs[kt], m, 0, 0, 0);
      }
      float* dst = agg + (size_t)d * HH + t * 16 + q * 4;
      atomicAdd(dst + 0, m[0] * sigm(g[0]));
      atomicAdd(dst + 1, m[1] * sigm(g[1]));
      atomicAdd(dst + 2, m[2] * sigm(g[2]));
      atomicAdd(dst + 3, m[3] * sigm(g[3]));
    }
  }
}

__global__ __launch_bounds__(512) void node_mfma(
    const float* __restrict__ hin, const float* __restrict__ agg,
    const float* __restrict__ w1, const float* __restrict__ b1,
    const float* __restrict__ w2, const float* __restrict__ b2,
    const float* __restrict__ lng, const float* __restrict__ lnb,
    float* __restrict__ out)
{
  __shared__ alignas(16) u16 w1t[128 * LDN1];
  __shared__ alignas(16) u16 w2t[128 * LDN2];
  __shared__ float b1s[HH], b2s[HH], gsv[HH], bsv[HH];

  const int tid = threadIdx.x;
  for (int i = tid; i < 256 * 128; i += 512) {
    int k = i >> 7, f = i & 127;
    w1t[f * LDN1 + k] = f2bf(w1[i]);
  }
  for (int i = tid; i < 128 * 128; i += 512) {
    int k = i >> 7, f = i & 127;
    w2t[f * LDN2 + k] = f2bf(w2[i]);
  }
  if (tid < HH) { b1s[tid] = b1[tid]; b2s[tid] = b2[tid];
                  gsv[tid] = lng[tid]; bsv[tid] = lnb[tid]; }
  __syncthreads();

  const int lane = tid & 63;
  const int wid  = tid >> 6;
  const int q    = lane >> 4;
  const int nr   = lane & 15;
  const int gw   = blockIdx.x * NW + wid;
  const int nwv  = gridDim.x * NW;
  const int srcA = 2 * (q & 1) * 16 + nr;
  const int srcB = srcA + 16;
  const bool hiT = (q >> 1) != 0;

  for (int nb = gw; nb < NNB; nb += nwv) {
    const int n = nb * 16 + nr;
    const size_t base = (size_t)n * HH;

    bf16x8 cb[8];
    const float* hp = hin + base + q * 8;
    cb[0] = ld8f_bf(hp);
    cb[1] = ld8f_bf(hp + 32);
    cb[2] = ld8f_bf(hp + 64);
    cb[3] = ld8f_bf(hp + 96);
    const float* ap = agg + base + q * 8;
    cb[4] = ld8f_bf(ap);
    cb[5] = ld8f_bf(ap + 32);
    cb[6] = ld8f_bf(ap + 64);
    cb[7] = ld8f_bf(ap + 96);

    uint2 pku[8];
#pragma unroll
    for (int t = 0; t < 8; t++) {
      const u16* a1p = w1t + (t * 16 + nr) * LDN1 + q * 8;
      f32x4 acc = {b1s[t*16 + q*4 + 0], b1s[t*16 + q*4 + 1],
                   b1s[t*16 + q*4 + 2], b1s[t*16 + q*4 + 3]};
#pragma unroll
      for (int kt = 0; kt < 8; kt++) {
        bf16x8 af = *(const bf16x8*)(a1p + kt * 32);
        acc = __builtin_amdgcn_mfma_f32_16x16x32_bf16(af, cb[kt], acc, 0, 0, 0);
      }
      float v0 = fmaxf(acc[0], 0.0f), v1 = fmaxf(acc[1], 0.0f);
      float v2 = fmaxf(acc[2], 0.0f), v3 = fmaxf(acc[3], 0.0f);
      pku[t].x = ((u32)f2bf(v1) << 16) | f2bf(v0);
      pku[t].y = ((u32)f2bf(v3) << 16) | f2bf(v2);
    }

    bf16x8 yb[4];
#pragma unroll
    for (int kt = 0; kt < 4; kt++) {
      uint2 aLo = shfl64(pku[2*kt],     srcA);
      uint2 aHi = shfl64(pku[2*kt + 1], srcA);
      uint2 bLo = shfl64(pku[2*kt],     srcB);
      uint2 bHi = shfl64(pku[2*kt + 1], srcB);
      uint4 w;
      w.x = hiT ? aHi.x : aLo.x;
      w.y = hiT ? aHi.y : aLo.y;
      w.z = hiT ? bHi.x : bLo.x;
      w.w = hiT ? bHi.y : bLo.y;
      yb[kt] = __builtin_bit_cast(bf16x8, w);
    }

    float xv[8][4];
    float psum = 0.0f;
#pragma unroll
    for (int t = 0; t < 8; t++) {
      const u16* a2p = w2t + (t * 16 + nr) * LDN2 + q * 8;
      f32x4 uacc = {b2s[t*16 + q*4 + 0], b2s[t*16 + q*4 + 1],
                    b2s[t*16 + q*4 + 2], b2s[t*16 + q*4 + 3]};
#pragma unroll
      for (int kt = 0; kt < 4; kt++) {
        bf16x8 a2 = *(const bf16x8*)(a2p + kt * 32);
        uacc = __builtin_amdgcn_mfma_f32_16x16x32_bf16(a2, yb[kt], uacc, 0, 0, 0);
      }
      float4 hv = *(const float4*)(hin + base + t * 16 + q * 4);
      xv[t][0] = hv.x + uacc[0];
      xv[t][1] = hv.y + uacc[1];
      xv[t][2] = hv.z + uacc[2];
      xv[t][3] = hv.w + uacc[3];
      psum += xv[t][0] + xv[t][1] + xv[t][2] + xv[t][3];
    }
    psum += __shfl_xor(psum, 16, 64);
    psum += __shfl_xor(psum, 32, 64);
    float mu = psum * (1.0f / 128.0f);
    float pvar = 0.0f;
#pragma unroll
    for (int t = 0; t < 8; t++) {
#pragma unroll
      for (int j = 0; j < 4; j++) {
        float dx = xv[t][j] - mu;
        xv[t][j] = dx;
        pvar += dx * dx;
      }
    }
    pvar += __shfl_xor(pvar, 16, 64);
    pvar += __shfl_xor(pvar, 32, 64);
    float inv = rsqrtf(pvar * (1.0f / 128.0f) + 1e-5f);
#pragma unroll
    for (int t = 0; t < 8; t++) {
      int F = t * 16 + q * 4;
      float4 ov;
      ov.x = xv[t][0] * inv * gsv[F + 0] + bsv[F + 0];
      ov.y = xv[t][1] * inv * gsv[F + 1] + bsv[F + 1];
      ov.z = xv[t][2] * inv * gsv[F + 2] + bsv[F + 2];
      ov.w = xv[t][3] * inv * gsv[F + 3] + bsv[F + 3];
      *(float4*)(out + base + F) = ov;
    }
  }
}

// ===========================================================================
extern "C" void kernel_launch(void* const* d_in, const int* in_sizes, int n_in,
                              void* d_out, int out_size, void* d_ws, size_t ws_size,
                              hipStream_t stream) {
  const float* h_hidden = (const float*)d_in[0];
  const float* h_clue   = (const float*)d_in[1];
  const int*   edges    = (const int*)d_in[2];
  const float* eattr    = (const float*)d_in[3];
  const float* c2h_g_w1 = (const float*)d_in[4];  const float* c2h_g_b1 = (const float*)d_in[5];
  const float* c2h_g_w2 = (const float*)d_in[6];  const float* c2h_g_b2 = (const float*)d_in[7];
  const float* c2h_m_w  = (const float*)d_in[8];  const float* c2h_m_b  = (const float*)d_in[9];
  const float* h_u_w1   = (const float*)d_in[10]; const float* h_u_b1   = (const float*)d_in[11];
  const float* h_u_w2   = (const float*)d_in[12]; const float* h_u_b2   = (const float*)d_in[13];
  const float* h_ln_g   = (const float*)d_in[14]; const float* h_ln_b   = (const float*)d_in[15];
  const float* h2c_g_w1 = (const float*)d_in[16]; const float* h2c_g_b1 = (const float*)d_in[17];
  const float* h2c_g_w2 = (const float*)d_in[18]; const float* h2c_g_b2 = (const float*)d_in[19];
  const float* h2c_m_w  = (const float*)d_in[20]; const float* h2c_m_b  = (const float*)d_in[21];
  const float* c_u_w1   = (const float*)d_in[22]; const float* c_u_b1   = (const float*)d_in[23];
  const float* c_u_w2   = (const float*)d_in[24]; const float* c_u_b2   = (const float*)d_in[25];
  const float* c_ln_g   = (const float*)d_in[26]; const float* c_ln_b   = (const float*)d_in[27];

  float* out_hidden = (float*)d_out;
  float* out_clue   = (float*)d_out + (size_t)NNODES * HH;

  // ---- workspace carve-up for the CSR path
  char* W = (char*)d_ws;
  size_t woff = 0;
  auto take = [&](size_t nbytes) -> char* {
    char* p = W + woff;
    woff += (nbytes + 255) & ~(size_t)255;
    return p;
  };
  u16* msgs   = (u16*)take((size_t)NEDGES * HH * 2);        // 128 MB
  int* cnt    = (int*)take((size_t)NNODES * 4);
  int* offA   = (int*)take((size_t)(NNODES + 1) * 4);
  int* offB   = (int*)take((size_t)(NNODES + 1) * 4);
  int* posA   = (int*)take((size_t)NNODES * 4);
  int* posB   = (int*)take((size_t)NNODES * 4);
  int* elistA = (int*)take((size_t)NEDGES * 4);
  int* elistB = (int*)take((size_t)NEDGES * 4);
  int* csum   = (int*)take((size_t)NCHUNK * 4);
  u16* gw1eA  = (u16*)take(128 * GE1 * 2);
  u16* gw2eA  = (u16*)take(128 * GE2 * 2);
  u16* gmweA  = (u16*)take(128 * GE2 * 2);
  u16* gw1nA  = (u16*)take(128 * GN1 * 2);
  u16* gw2nA  = (u16*)take(128 * GN2 * 2);
  u16* gw1eB  = (u16*)take(128 * GE1 * 2);
  u16* gw2eB  = (u16*)take(128 * GE2 * 2);
  u16* gmweB  = (u16*)take(128 * GE2 * 2);
  u16* gw1nB  = (u16*)take(128 * GN1 * 2);
  u16* gw2nB  = (u16*)take(128 * GN2 * 2);

  if (ws_size >= woff) {
    // ================= fast path: no atomics, CSR pull-aggregation =========
    const int EB = (NEDGES + 255) / 256;
    const int NB = (NNODES + 255) / 256;

    // stage all weights (bf16, transposed) — 2 launches
    stage_weights<<<dim3(16, 5), 256, 0, stream>>>(
        c2h_g_w1, c2h_g_w2, c2h_m_w, h_u_w1, h_u_w2,
        gw1eA, gw2eA, gmweA, gw1nA, gw2nA);
    stage_weights<<<dim3(16, 5), 256, 0, stream>>>(
        h2c_g_w1, h2c_g_w2, h2c_m_w, c_u_w1, c_u_w2,
        gw1eB, gw2eB, gmweB, gw1nB, gw2nB);

    // CSR A: dst = edges[:,1]
    hipMemsetAsync(cnt, 0, (size_t)NNODES * 4, stream);
    count_k<<<EB, 256, 0, stream>>>(edges, 1, cnt);
    scanA_k<<<NCHUNK, CHUNK, 0, stream>>>(cnt, offA, csum);
    scanB_k<<<1, 64, 0, stream>>>(csum);
    scanC_k<<<NB, 256, 0, stream>>>(offA, posA, csum);
    fill_k<<<EB, 256, 0, stream>>>(edges, 1, posA, elistA);

    // CSR B: dst = edges[:,0]
    hipMemsetAsync(cnt, 0, (size_t)NNODES * 4, stream);
    count_k<<<EB, 256, 0, stream>>>(edges, 0, cnt);
    scanA_k<<<NCHUNK, CHUNK, 0, stream>>>(cnt, offB, csum);
    scanB_k<<<1, 64, 0, stream>>>(csum);
    scanC_k<<<NB, 256, 0, stream>>>(offB, posB, csum);
    fill_k<<<EB, 256, 0, stream>>>(edges, 0, posB, elistB);

    // Phase 1: clue -> hidden
    edge_msg_w<<<1024, 512, 0, stream>>>(h_clue, edges, eattr,
        gw1eA, c2h_g_b1, gw2eA, c2h_g_b2, gmweA, c2h_m_b, msgs, 0);
    node_csr<<<512, 512, 0, stream>>>(h_hidden, msgs, offA, elistA,
        gw1nA, h_u_b1, gw2nA, h_u_b2, h_ln_g, h_ln_b, out_hidden);

    // Phase 2: hidden_new -> clue
    edge_msg_w<<<1024, 512, 0, stream>>>(out_hidden, edges, eattr,
        gw1eB, h2c_g_b1, gw2eB, h2c_g_b2, gmweB, h2c_m_b, msgs, 1);
    node_csr<<<512, 512, 0, stream>>>(h_clue, msgs, offB, elistB,
        gw1nB, c_u_b1, gw2nB, c_u_b2, c_ln_g, c_ln_b, out_clue);
  } else {
    // ================= fallback: round-7 verified path ======================
    float* agg = (float*)d_ws;
    const size_t aggBytes = (size_t)NNODES * HH * sizeof(float);

    hipMemsetAsync(agg, 0, aggBytes, stream);
    edge_mfma<<<256, 512, 0, stream>>>(h_clue, edges, eattr,
        c2h_g_w1, c2h_g_b1, c2h_g_w2, c2h_g_b2, c2h_m_w, c2h_m_b, agg, 0);
    node_mfma<<<256, 512, 0, stream>>>(h_hidden, agg,
        h_u_w1, h_u_b1, h_u_w2, h_u_b2, h_ln_g, h_ln_b, out_hidden);

    hipMemsetAsync(agg, 0, aggBytes, stream);
    edge_mfma<<<256, 512, 0, stream>>>(out_hidden, edges, eattr,
        h2c_g_w1, h2c_g_b1, h2c_g_w2, h2c_g_b2, h2c_m_w, h2c_m_b, agg, 1);
    node_mfma<<<256, 512, 0, stream>>>(h_clue, agg,
        c_u_w1, c_u_b1, c_u_w2, c_u_b2, c_ln_g, c_ln_b, out_clue);
  }
}

// Round 9
// 1732.162 us; speedup vs baseline: 2.8569x; 1.2706x over previous
//
#include <hip/hip_runtime.h>

#define HH 128
#define EAA 16
#define NNODES 100000
#define NEDGES 500000
#define NBATCH (NEDGES / 16)   // 31250 exact
#define NNB    (NNODES / 16)   // 6250 exact
#define CHUNK 512
#define NCHUNK ((NNODES + CHUNK - 1) / CHUNK)  // 196

// global transposed-weight row strides (elements, 16B-multiple)
#define GE1 160   // edge w1t: k in [0,160), real 144, pad zeroed
#define GE2 128
#define GN1 256
#define GN2 128
#define NW 8      // waves per block
#define LROW 136  // LDS row stride in u16 (272 B = 17*16)

typedef unsigned int u32;
typedef unsigned short u16;
typedef __attribute__((ext_vector_type(8))) short bf16x8;
typedef __attribute__((ext_vector_type(4))) short s16x4;
typedef __attribute__((ext_vector_type(4))) float f32x4;

__device__ __forceinline__ float bf_lo(u32 v){ return __builtin_bit_cast(float, (u32)(v << 16)); }
__device__ __forceinline__ float bf_hi(u32 v){ return __builtin_bit_cast(float, (u32)(v & 0xffff0000u)); }
__device__ __forceinline__ u16 f2bf(float f){
  u32 x = __builtin_bit_cast(u32, f);
  return (u16)((x + 0x7fffu + ((x >> 16) & 1u)) >> 16);
}
__device__ __forceinline__ float sigm(float x){ return 1.0f / (1.0f + __expf(-x)); }
__device__ __forceinline__ uint2 shfl64(uint2 v, int src){
  uint2 r;
  r.x = (u32)__shfl((int)v.x, src, 64);
  r.y = (u32)__shfl((int)v.y, src, 64);
  return r;
}
__device__ __forceinline__ bf16x8 ld8f_bf(const float* p){
  float4 v0 = *(const float4*)(p);
  float4 v1 = *(const float4*)(p + 4);
  uint4 u;
  u.x = ((u32)f2bf(v0.y) << 16) | f2bf(v0.x);
  u.y = ((u32)f2bf(v0.w) << 16) | f2bf(v0.z);
  u.z = ((u32)f2bf(v1.y) << 16) | f2bf(v1.x);
  u.w = ((u32)f2bf(v1.w) << 16) | f2bf(v1.z);
  return __builtin_bit_cast(bf16x8, u);
}

// ===========================================================================
// Weight staging: transpose f32 [K][128] -> bf16 [128][Kpad] (zero pad).
// ===========================================================================
__global__ void stage_weights(
    const float* __restrict__ w1e, const float* __restrict__ w2e, const float* __restrict__ mwe,
    const float* __restrict__ w1n, const float* __restrict__ w2n,
    u16* __restrict__ gw1e, u16* __restrict__ gw2e, u16* __restrict__ gmwe,
    u16* __restrict__ gw1n, u16* __restrict__ gw2n)
{
  const float* src; u16* dst; int K, KP;
  switch (blockIdx.y) {
    case 0: src = w1e; dst = gw1e; K = 144; KP = GE1; break;
    case 1: src = w2e; dst = gw2e; K = 128; KP = GE2; break;
    case 2: src = mwe; dst = gmwe; K = 128; KP = GE2; break;
    case 3: src = w1n; dst = gw1n; K = 256; KP = GN1; break;
    default: src = w2n; dst = gw2n; K = 128; KP = GN2; break;
  }
  int total = 128 * KP;
  for (int i = blockIdx.x * blockDim.x + threadIdx.x; i < total; i += gridDim.x * blockDim.x) {
    int f = i / KP, k = i - f * KP;
    dst[i] = (k < K) ? f2bf(src[(size_t)k * 128 + f]) : (u16)0;
  }
}

// ===========================================================================
// CSR build: count -> 3-kernel exclusive scan -> fill
// ===========================================================================
__global__ void count_k(const int* __restrict__ edges, int col, int* __restrict__ cnt){
  int e = blockIdx.x * blockDim.x + threadIdx.x;
  if (e < NEDGES) atomicAdd(&cnt[edges[2 * e + col]], 1);
}
__global__ void scanA_k(const int* __restrict__ cnt, int* __restrict__ off, int* __restrict__ csum){
  __shared__ int ws[8];
  int i = blockIdx.x * CHUNK + threadIdx.x;
  int v = (i < NNODES) ? cnt[i] : 0;
  int lane = threadIdx.x & 63, w = threadIdx.x >> 6;
  int s = v;
#pragma unroll
  for (int d = 1; d < 64; d <<= 1){ int t = __shfl_up(s, d, 64); if (lane >= d) s += t; }
  if (lane == 63) ws[w] = s;
  __syncthreads();
  if (threadIdx.x == 0){
    int a = 0;
    for (int k = 0; k < 8; k++){ int t = ws[k]; ws[k] = a; a += t; }
    csum[blockIdx.x] = a;
  }
  __syncthreads();
  if (i < NNODES) off[i] = (s - v) + ws[w];
}
__global__ void scanB_k(int* __restrict__ csum){
  if (threadIdx.x == 0 && blockIdx.x == 0){
    int a = 0;
    for (int k = 0; k < NCHUNK; k++){ int t = csum[k]; csum[k] = a; a += t; }
  }
}
__global__ void scanC_k(int* __restrict__ off, int* __restrict__ pos, const int* __restrict__ csum){
  int i = blockIdx.x * blockDim.x + threadIdx.x;
  if (i < NNODES){ int v = off[i] + csum[i / CHUNK]; off[i] = v; pos[i] = v; }
  if (i == 0) off[NNODES] = NEDGES;
}
__global__ void fill_k(const int* __restrict__ edges, int col, int* __restrict__ pos, int* __restrict__ elist){
  int e = blockIdx.x * blockDim.x + threadIdx.x;
  if (e < NEDGES){ int d = edges[2 * e + col]; int p = atomicAdd(&pos[d], 1); elist[p] = e; }
}

// ===========================================================================
// Edge message kernel. 16 edges/wave. Coalesced row gather via LDS transpose;
// blocked msgs layout [batch][t][er][qw] (32 B per (b,t,er) chunk).
// ===========================================================================
__global__ __launch_bounds__(512, 2) void edge_msg_w(
    const float* __restrict__ srcN, const int* __restrict__ edges,
    const float* __restrict__ eattr,
    const u16* __restrict__ w1t, const float* __restrict__ b1,
    const u16* __restrict__ w2t, const float* __restrict__ b2,
    const u16* __restrict__ mwt, const float* __restrict__ mb,
    u16* __restrict__ msgs, int srcCol)
{
  __shared__ float b1s[HH], b2s[HH], mbs[HH];
  __shared__ alignas(16) u16 rows[NW][16 * LROW];   // 34816 B
  const int tid = threadIdx.x;
  if (tid < HH){ b1s[tid] = b1[tid]; b2s[tid] = b2[tid]; mbs[tid] = mb[tid]; }
  __syncthreads();

  const int lane = tid & 63;
  const int wid  = tid >> 6;
  const int q    = lane >> 4;
  const int er   = lane & 15;
  const int ll   = lane & 31;    // row-load lane
  const int half = lane >> 5;    // which of the 2 rows this half-wave loads
  const int gw   = blockIdx.x * NW + wid;
  const int nwv  = gridDim.x * NW;
  const int srcA = 2 * (q & 1) * 16 + er;
  const int srcB = srcA + 16;
  const bool hiT = (q >> 1) != 0;
  u16* myrows = rows[wid];

  for (int b = gw; b < NBATCH; b += nwv) {
    const int e0 = b * 16;
    int2 ep = ((const int2*)edges)[e0 + er];
    const int s = srcCol ? ep.y : ep.x;

    // ---- coalesced gather: half-wave loads one full 512-B row, bf16 -> LDS
#pragma unroll
    for (int p = 0; p < 8; p++) {
      int j = 2 * p + half;
      int sj = __shfl(s, j, 64);
      float4 v = *(const float4*)(srcN + (size_t)sj * HH + ll * 4);
      uint2 pk;
      pk.x = ((u32)f2bf(v.y) << 16) | f2bf(v.x);
      pk.y = ((u32)f2bf(v.w) << 16) | f2bf(v.z);
      *(s16x4*)(myrows + j * LROW + ll * 4) = __builtin_bit_cast(s16x4, pk);
    }
    asm volatile("" ::: "memory");   // order ds_writes before ds_reads

    // ---- B-frags from LDS (feats kt*32+q*8 of edge er) + eattr tail
    bf16x8 bs[5];
#pragma unroll
    for (int kt = 0; kt < 4; kt++)
      bs[kt] = *(const bf16x8*)(myrows + er * LROW + kt * 32 + q * 8);
    if (q < 2) bs[4] = ld8f_bf(eattr + (size_t)(e0 + er) * EAA + q * 8);
    else       bs[4] = (bf16x8){0,0,0,0,0,0,0,0};

    // ---- stage 1: y^T + SiLU
    uint2 pku[8];
#pragma unroll
    for (int t = 0; t < 8; t++) {
      const u16* ap = w1t + (size_t)(t * 16 + er) * GE1 + q * 8;
      f32x4 acc = {b1s[t*16 + q*4 + 0], b1s[t*16 + q*4 + 1],
                   b1s[t*16 + q*4 + 2], b1s[t*16 + q*4 + 3]};
#pragma unroll
      for (int kt = 0; kt < 5; kt++) {
        bf16x8 af = *(const bf16x8*)(ap + kt * 32);
        acc = __builtin_amdgcn_mfma_f32_16x16x32_bf16(af, bs[kt], acc, 0, 0, 0);
      }
      float v0 = acc[0] * sigm(acc[0]), v1 = acc[1] * sigm(acc[1]);
      float v2 = acc[2] * sigm(acc[2]), v3 = acc[3] * sigm(acc[3]);
      pku[t].x = ((u32)f2bf(v1) << 16) | f2bf(v0);
      pku[t].y = ((u32)f2bf(v3) << 16) | f2bf(v2);
    }

    // ---- D-layout -> B-frag redistribution (in-register)
    bf16x8 yb[4];
#pragma unroll
    for (int kt = 0; kt < 4; kt++) {
      uint2 aLo = shfl64(pku[2*kt],     srcA);
      uint2 aHi = shfl64(pku[2*kt + 1], srcA);
      uint2 bLo = shfl64(pku[2*kt],     srcB);
      uint2 bHi = shfl64(pku[2*kt + 1], srcB);
      uint4 w;
      w.x = hiT ? aHi.x : aLo.x;
      w.y = hiT ? aHi.y : aLo.y;
      w.z = hiT ? bHi.x : bLo.x;
      w.w = hiT ? bHi.y : bLo.y;
      yb[kt] = __builtin_bit_cast(bf16x8, w);
    }

    // ---- stage 2+3: gate & message; blocked coalesced store
#pragma unroll
    for (int t = 0; t < 8; t++) {
      const u16* ap2 = w2t + (size_t)(t * 16 + er) * GE2 + q * 8;
      const u16* ap3 = mwt + (size_t)(t * 16 + er) * GE2 + q * 8;
      f32x4 g = {b2s[t*16 + q*4 + 0], b2s[t*16 + q*4 + 1],
                 b2s[t*16 + q*4 + 2], b2s[t*16 + q*4 + 3]};
      f32x4 m = {mbs[t*16 + q*4 + 0], mbs[t*16 + q*4 + 1],
                 mbs[t*16 + q*4 + 2], mbs[t*16 + q*4 + 3]};
#pragma unroll
      for (int kt = 0; kt < 4; kt++) {
        bf16x8 a2 = *(const bf16x8*)(ap2 + kt * 32);
        g = __builtin_amdgcn_mfma_f32_16x16x32_bf16(a2, yb[kt], g, 0, 0, 0);
        bf16x8 a3 = *(const bf16x8*)(ap3 + kt * 32);
        m = __builtin_amdgcn_mfma_f32_16x16x32_bf16(a3, bs[kt], m, 0, 0, 0);
      }
      float v0 = m[0] * sigm(g[0]), v1 = m[1] * sigm(g[1]);
      float v2 = m[2] * sigm(g[2]), v3 = m[3] * sigm(g[3]);
      uint2 pk;
      pk.x = ((u32)f2bf(v1) << 16) | f2bf(v0);
      pk.y = ((u32)f2bf(v3) << 16) | f2bf(v2);
      // chunk (b, t, er): 32 B; slot qw=q: 8 B. Wave store = 512 B contiguous.
      *(s16x4*)(msgs + (((size_t)b * 8 + t) * 16 + er) * 16 + q * 4) =
          __builtin_bit_cast(s16x4, pk);
    }
  }
}

// ===========================================================================
// Node update with CSR pull-aggregation. 16 nodes/wave. Blocked-msg reader.
// ===========================================================================
__global__ __launch_bounds__(512, 2) void node_csr(
    const float* __restrict__ hin,
    const u16* __restrict__ msgs, const int* __restrict__ off, const int* __restrict__ elist,
    const u16* __restrict__ w1t, const float* __restrict__ b1,
    const u16* __restrict__ w2t, const float* __restrict__ b2,
    const float* __restrict__ lng, const float* __restrict__ lnb,
    float* __restrict__ out)
{
  __shared__ float b1s[HH], b2s[HH], gsv[HH], bsv[HH];
  const int tid = threadIdx.x;
  if (tid < HH){ b1s[tid] = b1[tid]; b2s[tid] = b2[tid];
                 gsv[tid] = lng[tid]; bsv[tid] = lnb[tid]; }
  __syncthreads();

  const int lane = tid & 63;
  const int wid  = tid >> 6;
  const int q    = lane >> 4;
  const int nr   = lane & 15;
  const int gw   = blockIdx.x * NW + wid;
  const int nwv  = gridDim.x * NW;
  const int srcA = 2 * (q & 1) * 16 + nr;
  const int srcB = srcA + 16;
  const bool hiT = (q >> 1) != 0;

  for (int nb = gw; nb < NNB; nb += nwv) {
    const int n = nb * 16 + nr;
    const size_t base = (size_t)n * HH;

    // ---- pull-aggregate this node's messages (f32 accum in registers)
    float av[32];
#pragma unroll
    for (int j = 0; j < 32; j++) av[j] = 0.0f;
    const int beg = off[n], end = off[n + 1];
    for (int i = 0; ; i++) {
      bool act = (beg + i < end);
      if (!__any(act)) break;
      if (act) {
        int eid = elist[beg + i];
        int eb = eid >> 4, er = eid & 15;
#pragma unroll
        for (int kt = 0; kt < 4; kt++) {
          int t = 2 * kt + (q >> 1);
          uint4 r = *(const uint4*)(msgs +
              (((size_t)eb * 8 + t) * 16 + er) * 16 + (q & 1) * 8);
          av[kt*8+0] += bf_lo(r.x); av[kt*8+1] += bf_hi(r.x);
          av[kt*8+2] += bf_lo(r.y); av[kt*8+3] += bf_hi(r.y);
          av[kt*8+4] += bf_lo(r.z); av[kt*8+5] += bf_hi(r.z);
          av[kt*8+6] += bf_lo(r.w); av[kt*8+7] += bf_hi(r.w);
        }
      }
    }

    // ---- B-frags: cat = [hin | agg]
    bf16x8 cb[8];
    const float* hp = hin + base + q * 8;
    cb[0] = ld8f_bf(hp);
    cb[1] = ld8f_bf(hp + 32);
    cb[2] = ld8f_bf(hp + 64);
    cb[3] = ld8f_bf(hp + 96);
#pragma unroll
    for (int kt = 0; kt < 4; kt++) {
      uint4 u;
      u.x = ((u32)f2bf(av[kt*8+1]) << 16) | f2bf(av[kt*8+0]);
      u.y = ((u32)f2bf(av[kt*8+3]) << 16) | f2bf(av[kt*8+2]);
      u.z = ((u32)f2bf(av[kt*8+5]) << 16) | f2bf(av[kt*8+4]);
      u.w = ((u32)f2bf(av[kt*8+7]) << 16) | f2bf(av[kt*8+6]);
      cb[4 + kt] = __builtin_bit_cast(bf16x8, u);
    }

    // ---- stage 1: u^T = relu(w1^T @ cat^T + b1)
    uint2 pku[8];
#pragma unroll
    for (int t = 0; t < 8; t++) {
      const u16* a1p = w1t + (size_t)(t * 16 + nr) * GN1 + q * 8;
      f32x4 acc = {b1s[t*16 + q*4 + 0], b1s[t*16 + q*4 + 1],
                   b1s[t*16 + q*4 + 2], b1s[t*16 + q*4 + 3]};
#pragma unroll
      for (int kt = 0; kt < 8; kt++) {
        bf16x8 af = *(const bf16x8*)(a1p + kt * 32);
        acc = __builtin_amdgcn_mfma_f32_16x16x32_bf16(af, cb[kt], acc, 0, 0, 0);
      }
      float v0 = fmaxf(acc[0], 0.0f), v1 = fmaxf(acc[1], 0.0f);
      float v2 = fmaxf(acc[2], 0.0f), v3 = fmaxf(acc[3], 0.0f);
      pku[t].x = ((u32)f2bf(v1) << 16) | f2bf(v0);
      pku[t].y = ((u32)f2bf(v3) << 16) | f2bf(v2);
    }

    bf16x8 yb[4];
#pragma unroll
    for (int kt = 0; kt < 4; kt++) {
      uint2 aLo = shfl64(pku[2*kt],     srcA);
      uint2 aHi = shfl64(pku[2*kt + 1], srcA);
      uint2 bLo = shfl64(pku[2*kt],     srcB);
      uint2 bHi = shfl64(pku[2*kt + 1], srcB);
      uint4 w;
      w.x = hiT ? aHi.x : aLo.x;
      w.y = hiT ? aHi.y : aLo.y;
      w.z = hiT ? bHi.x : bLo.x;
      w.w = hiT ? bHi.y : bLo.y;
      yb[kt] = __builtin_bit_cast(bf16x8, w);
    }

    // ---- stage 2 + residual + LN
    float xv[8][4];
    float psum = 0.0f;
#pragma unroll
    for (int t = 0; t < 8; t++) {
      const u16* a2p = w2t + (size_t)(t * 16 + nr) * GN2 + q * 8;
      f32x4 uacc = {b2s[t*16 + q*4 + 0], b2s[t*16 + q*4 + 1],
                    b2s[t*16 + q*4 + 2], b2s[t*16 + q*4 + 3]};
#pragma unroll
      for (int kt = 0; kt < 4; kt++) {
        bf16x8 a2 = *(const bf16x8*)(a2p + kt * 32);
        uacc = __builtin_amdgcn_mfma_f32_16x16x32_bf16(a2, yb[kt], uacc, 0, 0, 0);
      }
      float4 hv = *(const float4*)(hin + base + t * 16 + q * 4);
      xv[t][0] = hv.x + uacc[0];
      xv[t][1] = hv.y + uacc[1];
      xv[t][2] = hv.z + uacc[2];
      xv[t][3] = hv.w + uacc[3];
      psum += xv[t][0] + xv[t][1] + xv[t][2] + xv[t][3];
    }
    psum += __shfl_xor(psum, 16, 64);
    psum += __shfl_xor(psum, 32, 64);
    float mu = psum * (1.0f / 128.0f);
    float pvar = 0.0f;
#pragma unroll
    for (int t = 0; t < 8; t++) {
#pragma unroll
      for (int j = 0; j < 4; j++) {
        float dx = xv[t][j] - mu;
        xv[t][j] = dx;
        pvar += dx * dx;
      }
    }
    pvar += __shfl_xor(pvar, 16, 64);
    pvar += __shfl_xor(pvar, 32, 64);
    float inv = rsqrtf(pvar * (1.0f / 128.0f) + 1e-5f);
#pragma unroll
    for (int t = 0; t < 8; t++) {
      int F = t * 16 + q * 4;
      float4 ov;
      ov.x = xv[t][0] * inv * gsv[F + 0] + bsv[F + 0];
      ov.y = xv[t][1] * inv * gsv[F + 1] + bsv[F + 1];
      ov.z = xv[t][2] * inv * gsv[F + 2] + bsv[F + 2];
      ov.w = xv[t][3] * inv * gsv[F + 3] + bsv[F + 3];
      *(float4*)(out + base + F) = ov;
    }
  }
}

// ===========================================================================
extern "C" void kernel_launch(void* const* d_in, const int* in_sizes, int n_in,
                              void* d_out, int out_size, void* d_ws, size_t ws_size,
                              hipStream_t stream) {
  const float* h_hidden = (const float*)d_in[0];
  const float* h_clue   = (const float*)d_in[1];
  const int*   edges    = (const int*)d_in[2];
  const float* eattr    = (const float*)d_in[3];
  const float* c2h_g_w1 = (const float*)d_in[4];  const float* c2h_g_b1 = (const float*)d_in[5];
  const float* c2h_g_w2 = (const float*)d_in[6];  const float* c2h_g_b2 = (const float*)d_in[7];
  const float* c2h_m_w  = (const float*)d_in[8];  const float* c2h_m_b  = (const float*)d_in[9];
  const float* h_u_w1   = (const float*)d_in[10]; const float* h_u_b1   = (const float*)d_in[11];
  const float* h_u_w2   = (const float*)d_in[12]; const float* h_u_b2   = (const float*)d_in[13];
  const float* h_ln_g   = (const float*)d_in[14]; const float* h_ln_b   = (const float*)d_in[15];
  const float* h2c_g_w1 = (const float*)d_in[16]; const float* h2c_g_b1 = (const float*)d_in[17];
  const float* h2c_g_w2 = (const float*)d_in[18]; const float* h2c_g_b2 = (const float*)d_in[19];
  const float* h2c_m_w  = (const float*)d_in[20]; const float* h2c_m_b  = (const float*)d_in[21];
  const float* c_u_w1   = (const float*)d_in[22]; const float* c_u_b1   = (const float*)d_in[23];
  const float* c_u_w2   = (const float*)d_in[24]; const float* c_u_b2   = (const float*)d_in[25];
  const float* c_ln_g   = (const float*)d_in[26]; const float* c_ln_b   = (const float*)d_in[27];

  float* out_hidden = (float*)d_out;
  float* out_clue   = (float*)d_out + (size_t)NNODES * HH;

  // ---- workspace carve-up (round-8 layout; proven to fit)
  char* W = (char*)d_ws;
  size_t woff = 0;
  auto take = [&](size_t nbytes) -> char* {
    char* p = W + woff;
    woff += (nbytes + 255) & ~(size_t)255;
    return p;
  };
  u16* msgs   = (u16*)take((size_t)NEDGES * HH * 2);        // 128 MB
  int* cnt    = (int*)take((size_t)NNODES * 4);
  int* offA   = (int*)take((size_t)(NNODES + 1) * 4);
  int* offB   = (int*)take((size_t)(NNODES + 1) * 4);
  int* posA   = (int*)take((size_t)NNODES * 4);
  int* posB   = (int*)take((size_t)NNODES * 4);
  int* elistA = (int*)take((size_t)NEDGES * 4);
  int* elistB = (int*)take((size_t)NEDGES * 4);
  int* csum   = (int*)take((size_t)NCHUNK * 4);
  u16* gw1eA  = (u16*)take(128 * GE1 * 2);
  u16* gw2eA  = (u16*)take(128 * GE2 * 2);
  u16* gmweA  = (u16*)take(128 * GE2 * 2);
  u16* gw1nA  = (u16*)take(128 * GN1 * 2);
  u16* gw2nA  = (u16*)take(128 * GN2 * 2);
  u16* gw1eB  = (u16*)take(128 * GE1 * 2);
  u16* gw2eB  = (u16*)take(128 * GE2 * 2);
  u16* gmweB  = (u16*)take(128 * GE2 * 2);
  u16* gw1nB  = (u16*)take(128 * GN1 * 2);
  u16* gw2nB  = (u16*)take(128 * GN2 * 2);

  const int EB = (NEDGES + 255) / 256;
  const int NB = (NNODES + 255) / 256;

  // stage all weights (bf16, transposed)
  stage_weights<<<dim3(16, 5), 256, 0, stream>>>(
      c2h_g_w1, c2h_g_w2, c2h_m_w, h_u_w1, h_u_w2,
      gw1eA, gw2eA, gmweA, gw1nA, gw2nA);
  stage_weights<<<dim3(16, 5), 256, 0, stream>>>(
      h2c_g_w1, h2c_g_w2, h2c_m_w, c_u_w1, c_u_w2,
      gw1eB, gw2eB, gmweB, gw1nB, gw2nB);

  // CSR A: dst = edges[:,1]
  hipMemsetAsync(cnt, 0, (size_t)NNODES * 4, stream);
  count_k<<<EB, 256, 0, stream>>>(edges, 1, cnt);
  scanA_k<<<NCHUNK, CHUNK, 0, stream>>>(cnt, offA, csum);
  scanB_k<<<1, 64, 0, stream>>>(csum);
  scanC_k<<<NB, 256, 0, stream>>>(offA, posA, csum);
  fill_k<<<EB, 256, 0, stream>>>(edges, 1, posA, elistA);

  // CSR B: dst = edges[:,0]
  hipMemsetAsync(cnt, 0, (size_t)NNODES * 4, stream);
  count_k<<<EB, 256, 0, stream>>>(edges, 0, cnt);
  scanA_k<<<NCHUNK, CHUNK, 0, stream>>>(cnt, offB, csum);
  scanB_k<<<1, 64, 0, stream>>>(csum);
  scanC_k<<<NB, 256, 0, stream>>>(offB, posB, csum);
  fill_k<<<EB, 256, 0, stream>>>(edges, 0, posB, elistB);

  // Phase 1: clue -> hidden
  edge_msg_w<<<1024, 512, 0, stream>>>(h_clue, edges, eattr,
      gw1eA, c2h_g_b1, gw2eA, c2h_g_b2, gmweA, c2h_m_b, msgs, 0);
  node_csr<<<512, 512, 0, stream>>>(h_hidden, msgs, offA, elistA,
      gw1nA, h_u_b1, gw2nA, h_u_b2, h_ln_g, h_ln_b, out_hidden);

  // Phase 2: hidden_new -> clue
  edge_msg_w<<<1024, 512, 0, stream>>>(out_hidden, edges, eattr,
      gw1eB, h2c_g_b1, gw2eB, h2c_g_b2, gmweB, h2c_m_b, msgs, 1);
  node_csr<<<512, 512, 0, stream>>>(h_clue, msgs, offB, elistB,
      gw1nB, c_u_b1, gw2nB, c_u_b2, c_ln_g, c_ln_b, out_clue);
}

// Round 10
// 1472.177 us; speedup vs baseline: 3.3614x; 1.1766x over previous
//
#include <hip/hip_runtime.h>

#define HH 128
#define EAA 16
#define NNODES 100000
#define NEDGES 500000
#define NBATCH (NEDGES / 16)   // 31250 exact
#define NNB    (NNODES / 16)   // 6250 exact
#define CHUNK 512
#define NCHUNK ((NNODES + CHUNK - 1) / CHUNK)  // 196

// global transposed-weight row strides (elements, 16B-multiple)
#define GE1 160   // edge w1t: k in [0,160), real 144, pad zeroed
#define GE2 128
#define GN1 256
#define GN2 128
#define NW 8      // waves per block
#define LROW 136  // src-rows LDS stride in u16 (272 B)
#define LROWM 140 // msg-tile LDS stride in u16 (280 B; 70%32=6 -> ~2-way banks)

typedef unsigned int u32;
typedef unsigned short u16;
typedef __attribute__((ext_vector_type(8))) short bf16x8;
typedef __attribute__((ext_vector_type(4))) short s16x4;
typedef __attribute__((ext_vector_type(4))) float f32x4;

__device__ __forceinline__ float bf_lo(u32 v){ return __builtin_bit_cast(float, (u32)(v << 16)); }
__device__ __forceinline__ float bf_hi(u32 v){ return __builtin_bit_cast(float, (u32)(v & 0xffff0000u)); }
__device__ __forceinline__ u16 f2bf(float f){
  u32 x = __builtin_bit_cast(u32, f);
  return (u16)((x + 0x7fffu + ((x >> 16) & 1u)) >> 16);
}
__device__ __forceinline__ float sigm(float x){ return 1.0f / (1.0f + __expf(-x)); }
__device__ __forceinline__ uint2 shfl64(uint2 v, int src){
  uint2 r;
  r.x = (u32)__shfl((int)v.x, src, 64);
  r.y = (u32)__shfl((int)v.y, src, 64);
  return r;
}
__device__ __forceinline__ float shflF(float v, int src){ return __shfl(v, src, 64); }
__device__ __forceinline__ bf16x8 ld8f_bf(const float* p){
  float4 v0 = *(const float4*)(p);
  float4 v1 = *(const float4*)(p + 4);
  uint4 u;
  u.x = ((u32)f2bf(v0.y) << 16) | f2bf(v0.x);
  u.y = ((u32)f2bf(v0.w) << 16) | f2bf(v0.z);
  u.z = ((u32)f2bf(v1.y) << 16) | f2bf(v1.x);
  u.w = ((u32)f2bf(v1.w) << 16) | f2bf(v1.z);
  return __builtin_bit_cast(bf16x8, u);
}

// ===========================================================================
// Weight staging: transpose f32 [K][128] -> bf16 [128][Kpad] (zero pad).
// ===========================================================================
__global__ void stage_weights(
    const float* __restrict__ w1e, const float* __restrict__ w2e, const float* __restrict__ mwe,
    const float* __restrict__ w1n, const float* __restrict__ w2n,
    u16* __restrict__ gw1e, u16* __restrict__ gw2e, u16* __restrict__ gmwe,
    u16* __restrict__ gw1n, u16* __restrict__ gw2n)
{
  const float* src; u16* dst; int K, KP;
  switch (blockIdx.y) {
    case 0: src = w1e; dst = gw1e; K = 144; KP = GE1; break;
    case 1: src = w2e; dst = gw2e; K = 128; KP = GE2; break;
    case 2: src = mwe; dst = gmwe; K = 128; KP = GE2; break;
    case 3: src = w1n; dst = gw1n; K = 256; KP = GN1; break;
    default: src = w2n; dst = gw2n; K = 128; KP = GN2; break;
  }
  int total = 128 * KP;
  for (int i = blockIdx.x * blockDim.x + threadIdx.x; i < total; i += gridDim.x * blockDim.x) {
    int f = i / KP, k = i - f * KP;
    dst[i] = (k < K) ? f2bf(src[(size_t)k * 128 + f]) : (u16)0;
  }
}

// ===========================================================================
// CSR build: count -> 3-kernel exclusive scan -> fill
// ===========================================================================
__global__ void count_k(const int* __restrict__ edges, int col, int* __restrict__ cnt){
  int e = blockIdx.x * blockDim.x + threadIdx.x;
  if (e < NEDGES) atomicAdd(&cnt[edges[2 * e + col]], 1);
}
__global__ void scanA_k(const int* __restrict__ cnt, int* __restrict__ off, int* __restrict__ csum){
  __shared__ int ws[8];
  int i = blockIdx.x * CHUNK + threadIdx.x;
  int v = (i < NNODES) ? cnt[i] : 0;
  int lane = threadIdx.x & 63, w = threadIdx.x >> 6;
  int s = v;
#pragma unroll
  for (int d = 1; d < 64; d <<= 1){ int t = __shfl_up(s, d, 64); if (lane >= d) s += t; }
  if (lane == 63) ws[w] = s;
  __syncthreads();
  if (threadIdx.x == 0){
    int a = 0;
    for (int k = 0; k < 8; k++){ int t = ws[k]; ws[k] = a; a += t; }
    csum[blockIdx.x] = a;
  }
  __syncthreads();
  if (i < NNODES) off[i] = (s - v) + ws[w];
}
__global__ void scanB_k(int* __restrict__ csum){
  if (threadIdx.x == 0 && blockIdx.x == 0){
    int a = 0;
    for (int k = 0; k < NCHUNK; k++){ int t = csum[k]; csum[k] = a; a += t; }
  }
}
__global__ void scanC_k(int* __restrict__ off, int* __restrict__ pos, const int* __restrict__ csum){
  int i = blockIdx.x * blockDim.x + threadIdx.x;
  if (i < NNODES){ int v = off[i] + csum[i / CHUNK]; off[i] = v; pos[i] = v; }
  if (i == 0) off[NNODES] = NEDGES;
}
__global__ void fill_k(const int* __restrict__ edges, int col, int* __restrict__ pos, int* __restrict__ elist){
  int e = blockIdx.x * blockDim.x + threadIdx.x;
  if (e < NEDGES){ int d = edges[2 * e + col]; int p = atomicAdd(&pos[d], 1); elist[p] = e; }
}

// ===========================================================================
// Edge message kernel. Processes edges in CSR (elist) order; msg of the
// edge at CSR position s is written to msgs[s*128 .. +128) bf16, so the
// node kernel can stream contiguous slot ranges. Store path: per-wave LDS
// tile -> lane-linear full-wave-contiguous 4KB block store.
// ===========================================================================
__global__ __launch_bounds__(512, 2) void edge_msg_w(
    const float* __restrict__ srcN, const int* __restrict__ edges,
    const int* __restrict__ elist,
    const float* __restrict__ eattr,
    const u16* __restrict__ w1t, const float* __restrict__ b1,
    const u16* __restrict__ w2t, const float* __restrict__ b2,
    const u16* __restrict__ mwt, const float* __restrict__ mb,
    u16* __restrict__ msgs, int srcCol)
{
  __shared__ float b1s[HH], b2s[HH], mbs[HH];
  __shared__ alignas(16) u16 rows[NW][16 * LROW];    // 34816 B
  __shared__ alignas(16) u16 msgt[NW][16 * LROWM];   // 35840 B
  const int tid = threadIdx.x;
  if (tid < HH){ b1s[tid] = b1[tid]; b2s[tid] = b2[tid]; mbs[tid] = mb[tid]; }
  __syncthreads();

  const int lane = tid & 63;
  const int wid  = tid >> 6;
  const int q    = lane >> 4;
  const int er   = lane & 15;
  const int ll   = lane & 31;    // row-load lane
  const int half = lane >> 5;    // which of the 2 rows this half-wave loads
  const int gw   = blockIdx.x * NW + wid;
  const int nwv  = gridDim.x * NW;
  const int srcA = 2 * (q & 1) * 16 + er;
  const int srcB = srcA + 16;
  const bool hiT = (q >> 1) != 0;
  u16* myrows = rows[wid];
  u16* mymsg  = msgt[wid];

  for (int b = gw; b < NBATCH; b += nwv) {
    const int e0 = b * 16;
    const int eid = elist[e0 + er];
    int2 ep = ((const int2*)edges)[eid];
    const int s = srcCol ? ep.y : ep.x;

    // ---- coalesced gather: half-wave loads one full 512-B row, bf16 -> LDS
#pragma unroll
    for (int p = 0; p < 8; p++) {
      int j = 2 * p + half;
      int sj = __shfl(s, j, 64);
      float4 v = *(const float4*)(srcN + (size_t)sj * HH + ll * 4);
      uint2 pk;
      pk.x = ((u32)f2bf(v.y) << 16) | f2bf(v.x);
      pk.y = ((u32)f2bf(v.w) << 16) | f2bf(v.z);
      *(s16x4*)(myrows + j * LROW + ll * 4) = __builtin_bit_cast(s16x4, pk);
    }
    asm volatile("" ::: "memory");   // order ds_writes before ds_reads

    // ---- B-frags from LDS + eattr tail (gathered by eid)
    bf16x8 bs[5];
#pragma unroll
    for (int kt = 0; kt < 4; kt++)
      bs[kt] = *(const bf16x8*)(myrows + er * LROW + kt * 32 + q * 8);
    if (q < 2) bs[4] = ld8f_bf(eattr + (size_t)eid * EAA + q * 8);
    else       bs[4] = (bf16x8){0,0,0,0,0,0,0,0};

    // ---- stage 1: y^T + SiLU
    uint2 pku[8];
#pragma unroll
    for (int t = 0; t < 8; t++) {
      const u16* ap = w1t + (size_t)(t * 16 + er) * GE1 + q * 8;
      f32x4 acc = {b1s[t*16 + q*4 + 0], b1s[t*16 + q*4 + 1],
                   b1s[t*16 + q*4 + 2], b1s[t*16 + q*4 + 3]};
#pragma unroll
      for (int kt = 0; kt < 5; kt++) {
        bf16x8 af = *(const bf16x8*)(ap + kt * 32);
        acc = __builtin_amdgcn_mfma_f32_16x16x32_bf16(af, bs[kt], acc, 0, 0, 0);
      }
      float v0 = acc[0] * sigm(acc[0]), v1 = acc[1] * sigm(acc[1]);
      float v2 = acc[2] * sigm(acc[2]), v3 = acc[3] * sigm(acc[3]);
      pku[t].x = ((u32)f2bf(v1) << 16) | f2bf(v0);
      pku[t].y = ((u32)f2bf(v3) << 16) | f2bf(v2);
    }

    // ---- D-layout -> B-frag redistribution (in-register)
    bf16x8 yb[4];
#pragma unroll
    for (int kt = 0; kt < 4; kt++) {
      uint2 aLo = shfl64(pku[2*kt],     srcA);
      uint2 aHi = shfl64(pku[2*kt + 1], srcA);
      uint2 bLo = shfl64(pku[2*kt],     srcB);
      uint2 bHi = shfl64(pku[2*kt + 1], srcB);
      uint4 w;
      w.x = hiT ? aHi.x : aLo.x;
      w.y = hiT ? aHi.y : aLo.y;
      w.z = hiT ? bHi.x : bLo.x;
      w.w = hiT ? bHi.y : bLo.y;
      yb[kt] = __builtin_bit_cast(bf16x8, w);
    }

    // ---- stage 2+3: gate & message -> LDS msg tile
#pragma unroll
    for (int t = 0; t < 8; t++) {
      const u16* ap2 = w2t + (size_t)(t * 16 + er) * GE2 + q * 8;
      const u16* ap3 = mwt + (size_t)(t * 16 + er) * GE2 + q * 8;
      f32x4 g = {b2s[t*16 + q*4 + 0], b2s[t*16 + q*4 + 1],
                 b2s[t*16 + q*4 + 2], b2s[t*16 + q*4 + 3]};
      f32x4 m = {mbs[t*16 + q*4 + 0], mbs[t*16 + q*4 + 1],
                 mbs[t*16 + q*4 + 2], mbs[t*16 + q*4 + 3]};
#pragma unroll
      for (int kt = 0; kt < 4; kt++) {
        bf16x8 a2 = *(const bf16x8*)(ap2 + kt * 32);
        g = __builtin_amdgcn_mfma_f32_16x16x32_bf16(a2, yb[kt], g, 0, 0, 0);
        bf16x8 a3 = *(const bf16x8*)(ap3 + kt * 32);
        m = __builtin_amdgcn_mfma_f32_16x16x32_bf16(a3, bs[kt], m, 0, 0, 0);
      }
      float v0 = m[0] * sigm(g[0]), v1 = m[1] * sigm(g[1]);
      float v2 = m[2] * sigm(g[2]), v3 = m[3] * sigm(g[3]);
      uint2 pk;
      pk.x = ((u32)f2bf(v1) << 16) | f2bf(v0);
      pk.y = ((u32)f2bf(v3) << 16) | f2bf(v2);
      *(s16x4*)(mymsg + er * LROWM + t * 16 + q * 4) = __builtin_bit_cast(s16x4, pk);
    }
    asm volatile("" ::: "memory");

    // ---- lane-linear contiguous 4KB block store (slots e0..e0+16)
    u16* base = msgs + (size_t)e0 * 128;
#pragma unroll
    for (int p = 0; p < 4; p++) {
      int j = p * 512 + lane * 8;          // u16 index within 2048-u16 block
      int row = j >> 7, col = j & 127;
      bf16x8 v = *(const bf16x8*)(mymsg + row * LROWM + col);
      *(bf16x8*)(base + j) = v;
    }
  }
}

// ===========================================================================
// Node update with CSR pull-aggregation. msgs are CSR-ordered: node n's
// messages occupy slots [off[n], off[n+1]) contiguously. Out-store goes
// through a 32-shfl lane transpose for quad-contiguous 64B writes.
// ===========================================================================
__global__ __launch_bounds__(512, 2) void node_csr(
    const float* __restrict__ hin,
    const u16* __restrict__ msgs, const int* __restrict__ off,
    const u16* __restrict__ w1t, const float* __restrict__ b1,
    const u16* __restrict__ w2t, const float* __restrict__ b2,
    const float* __restrict__ lng, const float* __restrict__ lnb,
    float* __restrict__ out)
{
  __shared__ float b1s[HH], b2s[HH], gsv[HH], bsv[HH];
  const int tid = threadIdx.x;
  if (tid < HH){ b1s[tid] = b1[tid]; b2s[tid] = b2[tid];
                 gsv[tid] = lng[tid]; bsv[tid] = lnb[tid]; }
  __syncthreads();

  const int lane = tid & 63;
  const int wid  = tid >> 6;
  const int q    = lane >> 4;
  const int nr   = lane & 15;
  const int gw   = blockIdx.x * NW + wid;
  const int nwv  = gridDim.x * NW;
  const int srcA = 2 * (q & 1) * 16 + nr;
  const int srcB = srcA + 16;
  const bool hiT = (q >> 1) != 0;
  const int nr2  = lane >> 2;       // out-store roles
  const int q2   = lane & 3;
  const int osrc = q2 * 16 + nr2;

  for (int nb = gw; nb < NNB; nb += nwv) {
    const int n = nb * 16 + nr;
    const size_t base = (size_t)n * HH;

    // ---- pull-aggregate: contiguous CSR slots of this node
    float av[32];
#pragma unroll
    for (int j = 0; j < 32; j++) av[j] = 0.0f;
    const int beg = off[n], end = off[n + 1];
    for (int i = 0; ; i++) {
      bool act = (beg + i < end);
      if (!__any(act)) break;
      if (act) {
        const u16* mp = msgs + (size_t)(beg + i) * 128 + q * 8;
#pragma unroll
        for (int kt = 0; kt < 4; kt++) {
          uint4 r = *(const uint4*)(mp + kt * 32);
          av[kt*8+0] += bf_lo(r.x); av[kt*8+1] += bf_hi(r.x);
          av[kt*8+2] += bf_lo(r.y); av[kt*8+3] += bf_hi(r.y);
          av[kt*8+4] += bf_lo(r.z); av[kt*8+5] += bf_hi(r.z);
          av[kt*8+6] += bf_lo(r.w); av[kt*8+7] += bf_hi(r.w);
        }
      }
    }

    // ---- B-frags: cat = [hin | agg]
    bf16x8 cb[8];
    const float* hp = hin + base + q * 8;
    cb[0] = ld8f_bf(hp);
    cb[1] = ld8f_bf(hp + 32);
    cb[2] = ld8f_bf(hp + 64);
    cb[3] = ld8f_bf(hp + 96);
#pragma unroll
    for (int kt = 0; kt < 4; kt++) {
      uint4 u;
      u.x = ((u32)f2bf(av[kt*8+1]) << 16) | f2bf(av[kt*8+0]);
      u.y = ((u32)f2bf(av[kt*8+3]) << 16) | f2bf(av[kt*8+2]);
      u.z = ((u32)f2bf(av[kt*8+5]) << 16) | f2bf(av[kt*8+4]);
      u.w = ((u32)f2bf(av[kt*8+7]) << 16) | f2bf(av[kt*8+6]);
      cb[4 + kt] = __builtin_bit_cast(bf16x8, u);
    }

    // ---- stage 1: u^T = relu(w1^T @ cat^T + b1)
    uint2 pku[8];
#pragma unroll
    for (int t = 0; t < 8; t++) {
      const u16* a1p = w1t + (size_t)(t * 16 + nr) * GN1 + q * 8;
      f32x4 acc = {b1s[t*16 + q*4 + 0], b1s[t*16 + q*4 + 1],
                   b1s[t*16 + q*4 + 2], b1s[t*16 + q*4 + 3]};
#pragma unroll
      for (int kt = 0; kt < 8; kt++) {
        bf16x8 af = *(const bf16x8*)(a1p + kt * 32);
        acc = __builtin_amdgcn_mfma_f32_16x16x32_bf16(af, cb[kt], acc, 0, 0, 0);
      }
      float v0 = fmaxf(acc[0], 0.0f), v1 = fmaxf(acc[1], 0.0f);
      float v2 = fmaxf(acc[2], 0.0f), v3 = fmaxf(acc[3], 0.0f);
      pku[t].x = ((u32)f2bf(v1) << 16) | f2bf(v0);
      pku[t].y = ((u32)f2bf(v3) << 16) | f2bf(v2);
    }

    bf16x8 yb[4];
#pragma unroll
    for (int kt = 0; kt < 4; kt++) {
      uint2 aLo = shfl64(pku[2*kt],     srcA);
      uint2 aHi = shfl64(pku[2*kt + 1], srcA);
      uint2 bLo = shfl64(pku[2*kt],     srcB);
      uint2 bHi = shfl64(pku[2*kt + 1], srcB);
      uint4 w;
      w.x = hiT ? aHi.x : aLo.x;
      w.y = hiT ? aHi.y : aLo.y;
      w.z = hiT ? bHi.x : bLo.x;
      w.w = hiT ? bHi.y : bLo.y;
      yb[kt] = __builtin_bit_cast(bf16x8, w);
    }

    // ---- stage 2 + residual + LN
    float xv[8][4];
    float psum = 0.0f;
#pragma unroll
    for (int t = 0; t < 8; t++) {
      const u16* a2p = w2t + (size_t)(t * 16 + nr) * GN2 + q * 8;
      f32x4 uacc = {b2s[t*16 + q*4 + 0], b2s[t*16 + q*4 + 1],
                    b2s[t*16 + q*4 + 2], b2s[t*16 + q*4 + 3]};
#pragma unroll
      for (int kt = 0; kt < 4; kt++) {
        bf16x8 a2 = *(const bf16x8*)(a2p + kt * 32);
        uacc = __builtin_amdgcn_mfma_f32_16x16x32_bf16(a2, yb[kt], uacc, 0, 0, 0);
      }
      float4 hv = *(const float4*)(hin + base + t * 16 + q * 4);
      xv[t][0] = hv.x + uacc[0];
      xv[t][1] = hv.y + uacc[1];
      xv[t][2] = hv.z + uacc[2];
      xv[t][3] = hv.w + uacc[3];
      psum += xv[t][0] + xv[t][1] + xv[t][2] + xv[t][3];
    }
    psum += __shfl_xor(psum, 16, 64);
    psum += __shfl_xor(psum, 32, 64);
    float mu = psum * (1.0f / 128.0f);
    float pvar = 0.0f;
#pragma unroll
    for (int t = 0; t < 8; t++) {
#pragma unroll
      for (int j = 0; j < 4; j++) {
        float dx = xv[t][j] - mu;
        xv[t][j] = dx;
        pvar += dx * dx;
      }
    }
    pvar += __shfl_xor(pvar, 16, 64);
    pvar += __shfl_xor(pvar, 32, 64);
    float inv = rsqrtf(pvar * (1.0f / 128.0f) + 1e-5f);
#pragma unroll
    for (int t = 0; t < 8; t++) {
      int F = t * 16 + q * 4;
      xv[t][0] = xv[t][0] * inv * gsv[F + 0] + bsv[F + 0];
      xv[t][1] = xv[t][1] * inv * gsv[F + 1] + bsv[F + 1];
      xv[t][2] = xv[t][2] * inv * gsv[F + 2] + bsv[F + 2];
      xv[t][3] = xv[t][3] * inv * gsv[F + 3] + bsv[F + 3];
    }

    // ---- transpose to (q2,nr2) roles; quad-contiguous 64B stores
    float* orow = out + (size_t)(nb * 16 + nr2) * HH;
#pragma unroll
    for (int t = 0; t < 8; t++) {
      float4 ov;
      ov.x = shflF(xv[t][0], osrc);
      ov.y = shflF(xv[t][1], osrc);
      ov.z = shflF(xv[t][2], osrc);
      ov.w = shflF(xv[t][3], osrc);
      *(float4*)(orow + t * 16 + q2 * 4) = ov;
    }
  }
}

// ===========================================================================
extern "C" void kernel_launch(void* const* d_in, const int* in_sizes, int n_in,
                              void* d_out, int out_size, void* d_ws, size_t ws_size,
                              hipStream_t stream) {
  const float* h_hidden = (const float*)d_in[0];
  const float* h_clue   = (const float*)d_in[1];
  const int*   edges    = (const int*)d_in[2];
  const float* eattr    = (const float*)d_in[3];
  const float* c2h_g_w1 = (const float*)d_in[4];  const float* c2h_g_b1 = (const float*)d_in[5];
  const float* c2h_g_w2 = (const float*)d_in[6];  const float* c2h_g_b2 = (const float*)d_in[7];
  const float* c2h_m_w  = (const float*)d_in[8];  const float* c2h_m_b  = (const float*)d_in[9];
  const float* h_u_w1   = (const float*)d_in[10]; const float* h_u_b1   = (const float*)d_in[11];
  const float* h_u_w2   = (const float*)d_in[12]; const float* h_u_b2   = (const float*)d_in[13];
  const float* h_ln_g   = (const float*)d_in[14]; const float* h_ln_b   = (const float*)d_in[15];
  const float* h2c_g_w1 = (const float*)d_in[16]; const float* h2c_g_b1 = (const float*)d_in[17];
  const float* h2c_g_w2 = (const float*)d_in[18]; const float* h2c_g_b2 = (const float*)d_in[19];
  const float* h2c_m_w  = (const float*)d_in[20]; const float* h2c_m_b  = (const float*)d_in[21];
  const float* c_u_w1   = (const float*)d_in[22]; const float* c_u_b1   = (const float*)d_in[23];
  const float* c_u_w2   = (const float*)d_in[24]; const float* c_u_b2   = (const float*)d_in[25];
  const float* c_ln_g   = (const float*)d_in[26]; const float* c_ln_b   = (const float*)d_in[27];

  float* out_hidden = (float*)d_out;
  float* out_clue   = (float*)d_out + (size_t)NNODES * HH;

  // ---- workspace carve-up
  char* W = (char*)d_ws;
  size_t woff = 0;
  auto take = [&](size_t nbytes) -> char* {
    char* p = W + woff;
    woff += (nbytes + 255) & ~(size_t)255;
    return p;
  };
  u16* msgs   = (u16*)take((size_t)NEDGES * HH * 2);        // 128 MB
  int* cnt    = (int*)take((size_t)NNODES * 4);
  int* offA   = (int*)take((size_t)(NNODES + 1) * 4);
  int* offB   = (int*)take((size_t)(NNODES + 1) * 4);
  int* posA   = (int*)take((size_t)NNODES * 4);
  int* posB   = (int*)take((size_t)NNODES * 4);
  int* elistA = (int*)take((size_t)NEDGES * 4);
  int* elistB = (int*)take((size_t)NEDGES * 4);
  int* csum   = (int*)take((size_t)NCHUNK * 4);
  u16* gw1eA  = (u16*)take(128 * GE1 * 2);
  u16* gw2eA  = (u16*)take(128 * GE2 * 2);
  u16* gmweA  = (u16*)take(128 * GE2 * 2);
  u16* gw1nA  = (u16*)take(128 * GN1 * 2);
  u16* gw2nA  = (u16*)take(128 * GN2 * 2);
  u16* gw1eB  = (u16*)take(128 * GE1 * 2);
  u16* gw2eB  = (u16*)take(128 * GE2 * 2);
  u16* gmweB  = (u16*)take(128 * GE2 * 2);
  u16* gw1nB  = (u16*)take(128 * GN1 * 2);
  u16* gw2nB  = (u16*)take(128 * GN2 * 2);

  const int EB = (NEDGES + 255) / 256;
  const int NB = (NNODES + 255) / 256;

  // stage all weights (bf16, transposed)
  stage_weights<<<dim3(16, 5), 256, 0, stream>>>(
      c2h_g_w1, c2h_g_w2, c2h_m_w, h_u_w1, h_u_w2,
      gw1eA, gw2eA, gmweA, gw1nA, gw2nA);
  stage_weights<<<dim3(16, 5), 256, 0, stream>>>(
      h2c_g_w1, h2c_g_w2, h2c_m_w, c_u_w1, c_u_w2,
      gw1eB, gw2eB, gmweB, gw1nB, gw2nB);

  // CSR A: dst = edges[:,1]
  hipMemsetAsync(cnt, 0, (size_t)NNODES * 4, stream);
  count_k<<<EB, 256, 0, stream>>>(edges, 1, cnt);
  scanA_k<<<NCHUNK, CHUNK, 0, stream>>>(cnt, offA, csum);
  scanB_k<<<1, 64, 0, stream>>>(csum);
  scanC_k<<<NB, 256, 0, stream>>>(offA, posA, csum);
  fill_k<<<EB, 256, 0, stream>>>(edges, 1, posA, elistA);

  // CSR B: dst = edges[:,0]
  hipMemsetAsync(cnt, 0, (size_t)NNODES * 4, stream);
  count_k<<<EB, 256, 0, stream>>>(edges, 0, cnt);
  scanA_k<<<NCHUNK, CHUNK, 0, stream>>>(cnt, offB, csum);
  scanB_k<<<1, 64, 0, stream>>>(csum);
  scanC_k<<<NB, 256, 0, stream>>>(offB, posB, csum);
  fill_k<<<EB, 256, 0, stream>>>(edges, 0, posB, elistB);

  // Phase 1: clue -> hidden (src = edges[:,0], agg over edges[:,1])
  edge_msg_w<<<1024, 512, 0, stream>>>(h_clue, edges, elistA, eattr,
      gw1eA, c2h_g_b1, gw2eA, c2h_g_b2, gmweA, c2h_m_b, msgs, 0);
  node_csr<<<512, 512, 0, stream>>>(h_hidden, msgs, offA,
      gw1nA, h_u_b1, gw2nA, h_u_b2, h_ln_g, h_ln_b, out_hidden);

  // Phase 2: hidden_new -> clue (src = edges[:,1], agg over edges[:,0])
  edge_msg_w<<<1024, 512, 0, stream>>>(out_hidden, edges, elistB, eattr,
      gw1eB, h2c_g_b1, gw2eB, h2c_g_b2, gmweB, h2c_m_b, msgs, 1);
  node_csr<<<512, 512, 0, stream>>>(h_clue, msgs, offB,
      gw1nB, c_u_b1, gw2nB, c_u_b2, c_ln_g, c_ln_b, out_clue);
}